// Round 6
// baseline (1109.580 us; speedup 1.0000x reference)
//
#include <hip/hip_runtime.h>
#include <hip/hip_bf16.h>
#include <math.h>

#define N_NODES 40000
#define E_EDGES 160000
#define ETOT    (E_EDGES + N_NODES)   // 200000 (with self-loops)
#define B_GRAPH 1024
#define FXD     78
#define H_HEADS 10
#define HF      (H_HEADS * FXD)       // 780
#define DOUT    128
#define DP      256

typedef __hip_bfloat16 bf16;
typedef __attribute__((ext_vector_type(8))) short short8;
typedef __attribute__((ext_vector_type(4))) float f32x4;

// ---------- ordered-float encoding for atomic max on unsigned ----------
static __device__ __forceinline__ unsigned f2o(float f) {
    unsigned u = __float_as_uint(f);
    return (u & 0x80000000u) ? ~u : (u | 0x80000000u);
}
static __device__ __forceinline__ float o2f(unsigned o) {
    unsigned u = (o & 0x80000000u) ? (o & 0x7FFFFFFFu) : ~o;
    return __uint_as_float(u);
}

static __device__ __forceinline__ void storev(float* p, float v) { *p = v; }
static __device__ __forceinline__ void storev(bf16* p, float v) { *p = __float2bfloat16(v); }
static __device__ __forceinline__ float loadv(const float* p) { return *p; }
static __device__ __forceinline__ float loadv(const bf16* p) { return __bfloat162float(*p); }

// edge e -> (src, dst); e >= E_EDGES are self-loops
static __device__ __forceinline__ void edge_sd(const int* __restrict__ ei, int e, int& s, int& d) {
    if (e < E_EDGES) { s = ei[e]; d = ei[E_EDGES + e]; }
    else             { s = e - E_EDGES; d = s; }
}

// ---------- fp32 -> bf16 convert ----------
__global__ void k_f2b(const float* __restrict__ in, bf16* __restrict__ out, int n) {
    int i = blockIdx.x * blockDim.x + threadIdx.x;
    if (i < n) out[i] = __float2bfloat16(in[i]);
}

// ---------- MFMA bf16 GEMM: C[M,N] = A[M,K] @ B[K,N] (+bias)(+relu) ----------
// BM=128, BN=128, BK=32; 256 threads = 4 waves, wave w -> rows [w*32, w*32+32).
// 1-D grid with XCD-grouped swizzle: all CT column-tiles of one row-tile share
// p%8, so under round-robin workgroup->XCD dispatch they hit the same XCD L2
// and the A row-tile is fetched from HBM once (R5: A was re-fetched 13x, 774MB).
template <typename OutT, int BIAS, int RELU>
__global__ __launch_bounds__(256)
void mfma_mm(const ushort* __restrict__ A, const ushort* __restrict__ Bw,
             const float* __restrict__ bias, OutT* __restrict__ C,
             int M, int K, int N) {
    const int RT = (M + 127) >> 7;
    const int CT = (N + 127) >> 7;
    const int p = blockIdx.x;
    const int r = (p & 7) + 8 * (p / (8 * CT));
    const int c = (p >> 3) % CT;
    if (r >= RT) return;
    const int m0 = r * 128;
    const int n0 = c * 128;

    __shared__ ushort As[128 * 40];   // row stride 40 (80B, 16B-aligned; 2-way ~free)
    __shared__ ushort Bs[128 * 40];   // transposed: Bs[n][k]
    const int tid = threadIdx.x;
    const int wave = tid >> 6, lane = tid & 63;
    const int quad = lane >> 4, l16 = lane & 15;

    f32x4 acc[2][8];
#pragma unroll
    for (int mi = 0; mi < 2; mi++)
#pragma unroll
        for (int ni = 0; ni < 8; ni++) acc[mi][ni] = (f32x4){0.f, 0.f, 0.f, 0.f};

    const int ar = tid >> 1;            // A stage: row 0..127
    const int ak = (tid & 1) * 16;      //          k offset 0/16
    const int bk = tid >> 4;            // B stage: k rows bk, bk+16
    const int bn = (tid & 15) * 8;      //          col offset 0..120

    for (int kb = 0; kb < K; kb += 32) {
        // ---- stage A tile [128 x 32] ----
        {
            int grow = m0 + ar;
            ushort tmp[16];
            if (grow < M && kb + ak + 16 <= K) {
                const uint* gp = (const uint*)(A + (size_t)grow * K + kb + ak);
#pragma unroll
                for (int v = 0; v < 8; v++) {
                    uint dd = gp[v];
                    tmp[2 * v] = (ushort)dd; tmp[2 * v + 1] = (ushort)(dd >> 16);
                }
            } else {
#pragma unroll
                for (int v = 0; v < 16; v++) {
                    int k = kb + ak + v;
                    tmp[v] = (grow < M && k < K) ? A[(size_t)grow * K + k] : (ushort)0;
                }
            }
#pragma unroll
            for (int v = 0; v < 16; v++) As[ar * 40 + ak + v] = tmp[v];
        }
        // ---- stage B tile [32 x 128] transposed into Bs[n][k] (2 k-rows/thread) ----
#pragma unroll
        for (int half = 0; half < 2; half++) {
            int krow = bk + half * 16;
            int gk = kb + krow;
            ushort tmp[8];
            if (gk < K && n0 + bn + 8 <= N) {
                const uint* gp = (const uint*)(Bw + (size_t)gk * N + n0 + bn);
#pragma unroll
                for (int v = 0; v < 4; v++) {
                    uint dd = gp[v];
                    tmp[2 * v] = (ushort)dd; tmp[2 * v + 1] = (ushort)(dd >> 16);
                }
            } else {
#pragma unroll
                for (int v = 0; v < 8; v++) {
                    int n = n0 + bn + v;
                    tmp[v] = (gk < K && n < N) ? Bw[(size_t)gk * N + n] : (ushort)0;
                }
            }
#pragma unroll
            for (int v = 0; v < 8; v++) Bs[(bn + v) * 40 + krow] = tmp[v];
        }
        __syncthreads();
        // ---- compute: 2x8 grid of 16x16x32 mfma ----
        const int wr = wave * 32;
        short8 af[2], bfr[8];
        af[0] = *(const short8*)&As[(wr + l16) * 40 + quad * 8];
        af[1] = *(const short8*)&As[(wr + 16 + l16) * 40 + quad * 8];
#pragma unroll
        for (int ni = 0; ni < 8; ni++)
            bfr[ni] = *(const short8*)&Bs[(ni * 16 + l16) * 40 + quad * 8];
#pragma unroll
        for (int mi = 0; mi < 2; mi++)
#pragma unroll
            for (int ni = 0; ni < 8; ni++)
                acc[mi][ni] = __builtin_amdgcn_mfma_f32_16x16x32_bf16(
                    af[mi], bfr[ni], acc[mi][ni], 0, 0, 0);
        __syncthreads();
    }
    // ---- epilogue: C row = quad*4+reg, col = lane&15 ----
#pragma unroll
    for (int mi = 0; mi < 2; mi++)
#pragma unroll
        for (int ni = 0; ni < 8; ni++)
#pragma unroll
            for (int rg = 0; rg < 4; rg++) {
                int row = m0 + wave * 32 + mi * 16 + quad * 4 + rg;
                int col = n0 + ni * 16 + l16;
                if (row < M && col < N) {
                    float v = acc[mi][ni][rg];
                    if (BIAS) v += bias[col];
                    if (RELU) v = fmaxf(v, 0.f);
                    storev(&C[(size_t)row * N + col], v);
                }
            }
}

static inline int mm_grid(int M, int N) {
    int RT = (M + 127) >> 7, CT = (N + 127) >> 7;
    int RTpad = ((RT + 7) >> 3) << 3;
    return RTpad * CT;
}

// ---------- protein fc ----------
__global__ void k_pv(const float* __restrict__ pvec, const float* __restrict__ w,
                     const float* __restrict__ b, float* __restrict__ pv) {
    __shared__ float sm[DP];
    int bg = blockIdx.x, t = threadIdx.x;
    sm[t] = pvec[(size_t)bg * DP + t];
    __syncthreads();
    float acc = 0.f;
    for (int k = 0; k < DP; k++) acc += sm[k] * w[(size_t)k * DP + t];
    pv[(size_t)bg * DP + t] = fmaxf(acc + b[t], 0.f);
}

// ---------- k/v projections ----------
__global__ void k_kv(const float* __restrict__ pv,
                     const float* __restrict__ kw, const float* __restrict__ kb,
                     const float* __restrict__ vw, const float* __restrict__ vb,
                     float* __restrict__ kbuf, float* __restrict__ vbuf) {
    __shared__ float sm[DP];
    int bg = blockIdx.x, t = threadIdx.x;
    sm[t] = pv[(size_t)bg * DP + t];
    __syncthreads();
    int o = t & 127;
    const float* w = (t < 128) ? kw : vw;
    const float* bb = (t < 128) ? kb : vb;
    float acc = 0.f;
    for (int k = 0; k < DP; k++) acc += sm[k] * w[(size_t)k * 128 + o];
    float v = acc + bb[o];
    if (t < 128) kbuf[(size_t)bg * 128 + o] = v;
    else         vbuf[(size_t)bg * 128 + o] = v;
}

// ---------- kq[b,k] = q_w @ k[b]; qbk[b] = q_b . k[b] ----------
__global__ void k_kq(const float* __restrict__ qw, const float* __restrict__ qb,
                     const float* __restrict__ kbuf, float* __restrict__ kq,
                     float* __restrict__ qbk) {
    __shared__ float kb[128];
    int b = blockIdx.x, t = threadIdx.x;  // 128 threads
    kb[t] = kbuf[(size_t)b * 128 + t];
    __syncthreads();
    float acc = 0.f;
    for (int o = 0; o < 128; o++) acc += qw[(size_t)t * 128 + o] * kb[o];
    kq[(size_t)b * 128 + t] = acc;
    if (t == 0) {
        float s = 0.f;
        for (int o = 0; o < 128; o++) s += qb[o] * kb[o];
        qbk[b] = s;
    }
}

// ---------- GAT per-node attention logits ----------
__global__ void k_att(const bf16* __restrict__ h, const float* __restrict__ aw_s,
                      const float* __restrict__ aw_d, float* __restrict__ asrc,
                      float* __restrict__ adst) {
    int i = blockIdx.x * blockDim.x + threadIdx.x;
    if (i >= N_NODES * H_HEADS) return;
    int n = i / H_HEADS, hh = i - n * H_HEADS;
    const bf16* hp = h + (size_t)n * HF + hh * FXD;
    const float* ws = aw_s + hh * FXD;
    const float* wd = aw_d + hh * FXD;
    float s1 = 0.f, s2 = 0.f;
    for (int c = 0; c < FXD; c++) { float v = loadv(&hp[c]); s1 += v * ws[c]; s2 += v * wd[c]; }
    asrc[i] = s1; adst[i] = s2;
}

// ---------- edge alpha + segment max over dst ----------
__global__ void k_alpha_max(const int* __restrict__ ei, const float* __restrict__ asrc,
                            const float* __restrict__ adst, float* __restrict__ alpha,
                            unsigned* __restrict__ mseg) {
    int i = blockIdx.x * blockDim.x + threadIdx.x;
    if (i >= ETOT * H_HEADS) return;
    int e = i / H_HEADS, hh = i - e * H_HEADS;
    int s, d; edge_sd(ei, e, s, d);
    float a = asrc[(size_t)s * H_HEADS + hh] + adst[(size_t)d * H_HEADS + hh];
    a = (a >= 0.f) ? a : 0.2f * a;
    alpha[i] = a;
    atomicMax(&mseg[(size_t)d * H_HEADS + hh], f2o(a));
}

// ---------- exp(alpha - m[dst]) in place + segment sum ----------
__global__ void k_exp_sum(const int* __restrict__ ei, float* __restrict__ alpha,
                          const unsigned* __restrict__ mseg, float* __restrict__ sseg) {
    int i = blockIdx.x * blockDim.x + threadIdx.x;
    if (i >= ETOT * H_HEADS) return;
    int e = i / H_HEADS, hh = i - e * H_HEADS;
    int s, d; edge_sd(ei, e, s, d);
    (void)s;
    float ex = expf(alpha[i] - o2f(mseg[(size_t)d * H_HEADS + hh]));
    alpha[i] = ex;
    atomicAdd(&sseg[(size_t)d * H_HEADS + hh], ex);
}

// ---------- CSR build: count, scan, scatter ----------
__global__ void k_count(const int* __restrict__ ei, int* __restrict__ cnt) {
    int e = blockIdx.x * blockDim.x + threadIdx.x;
    if (e >= ETOT) return;
    int d = (e < E_EDGES) ? ei[E_EDGES + e] : e - E_EDGES;
    atomicAdd(&cnt[d], 1);
}

__global__ void k_scan(const int* __restrict__ cnt, int* __restrict__ rowptr,
                       int* __restrict__ cursor) {  // 1 block, 1024 threads
    __shared__ int ps[1024];
    const int t = threadIdx.x;
    const int CH = 40;  // 1024*40 = 40960 >= 40000
    int base = t * CH;
    int s = 0;
    for (int i = 0; i < CH; i++) {
        int idx = base + i;
        if (idx < N_NODES) s += cnt[idx];
    }
    ps[t] = s;
    __syncthreads();
    for (int off = 1; off < 1024; off <<= 1) {
        int v = (t >= off) ? ps[t - off] : 0;
        __syncthreads();
        ps[t] += v;
        __syncthreads();
    }
    int run = (t == 0) ? 0 : ps[t - 1];
    for (int i = 0; i < CH; i++) {
        int idx = base + i;
        if (idx < N_NODES) {
            rowptr[idx] = run;
            cursor[idx] = run;
            run += cnt[idx];
        }
    }
    if (t == 1023) rowptr[N_NODES] = ps[1023];
}

__global__ void k_scatter(const int* __restrict__ ei, int* __restrict__ cursor,
                          int* __restrict__ elist) {
    int e = blockIdx.x * blockDim.x + threadIdx.x;
    if (e >= ETOT) return;
    int d = (e < E_EDGES) ? ei[E_EDGES + e] : e - E_EDGES;
    int pos = atomicAdd(&cursor[d], 1);
    elist[pos] = e;
}

__global__ void k_dinv(const int* __restrict__ cnt, float* __restrict__ dinv) {
    int n = blockIdx.x * blockDim.x + threadIdx.x;
    if (n >= N_NODES) return;
    int c = cnt[n];
    dinv[n] = (c > 0) ? 1.0f / sqrtf((float)c) : 0.f;
}

// ---------- GAT aggregation (CSR, no atomics) + fused bias+relu -> bf16 ----------
__global__ __launch_bounds__(256)
void k_gat_aggr_csr(const int* __restrict__ rowptr, const int* __restrict__ elist,
                    const int* __restrict__ ei, const bf16* __restrict__ h,
                    const float* __restrict__ eexp, const float* __restrict__ sseg,
                    const float* __restrict__ bias, bf16* __restrict__ outb) {
    __shared__ float sinv[H_HEADS];
    int d = blockIdx.x, t = threadIdx.x;
    if (t < H_HEADS) sinv[t] = 1.f / (sseg[(size_t)d * H_HEADS + t] + 1e-16f);
    __syncthreads();
    int beg = rowptr[d], end = rowptr[d + 1];
    const int c0 = t, c1 = t + 256, c2 = t + 512, c3 = 768 + t;  // c3 valid if t<12
    const int h0 = c0 / FXD, h1 = c1 / FXD, h2 = c2 / FXD;       // h3 == 9
    float a0 = 0.f, a1 = 0.f, a2 = 0.f, a3 = 0.f;
    for (int i = beg; i < end; i++) {
        int e = elist[i];
        int s, dd; edge_sd(ei, e, s, dd);
        const float* ex = eexp + (size_t)e * H_HEADS;
        const bf16* hr = h + (size_t)s * HF;
        a0 += ex[h0] * loadv(&hr[c0]);
        a1 += ex[h1] * loadv(&hr[c1]);
        a2 += ex[h2] * loadv(&hr[c2]);
        if (t < 12) a3 += ex[9] * loadv(&hr[c3]);
    }
    bf16* orow = outb + (size_t)d * HF;
    storev(&orow[c0], fmaxf(a0 * sinv[h0] + bias[c0], 0.f));
    storev(&orow[c1], fmaxf(a1 * sinv[h1] + bias[c1], 0.f));
    storev(&orow[c2], fmaxf(a2 * sinv[h2] + bias[c2], 0.f));
    if (t < 12) storev(&orow[c3], fmaxf(a3 * sinv[9] + bias[c3], 0.f));
}

// ---------- GCN aggregation (CSR, no atomics) + fused bias+relu -> bf16 ----------
__global__ __launch_bounds__(256)
void k_gcn_aggr_csr(const int* __restrict__ rowptr, const int* __restrict__ elist,
                    const int* __restrict__ ei, const bf16* __restrict__ hg,
                    const float* __restrict__ dinv, const float* __restrict__ bias,
                    bf16* __restrict__ outb) {
    int d = blockIdx.x, t = threadIdx.x;
    float dv = dinv[d];
    int beg = rowptr[d], end = rowptr[d + 1];
    const int c0 = t, c1 = t + 256, c2 = t + 512, c3 = 768 + t;
    float a0 = 0.f, a1 = 0.f, a2 = 0.f, a3 = 0.f;
    for (int i = beg; i < end; i++) {
        int e = elist[i];
        int s, dd; edge_sd(ei, e, s, dd);
        float w = dinv[s] * dv;
        const bf16* hr = hg + (size_t)s * HF;
        a0 += w * loadv(&hr[c0]);
        a1 += w * loadv(&hr[c1]);
        a2 += w * loadv(&hr[c2]);
        if (t < 12) a3 += w * loadv(&hr[c3]);
    }
    bf16* orow = outb + (size_t)d * HF;
    storev(&orow[c0], fmaxf(a0 + bias[c0], 0.f));
    storev(&orow[c1], fmaxf(a1 + bias[c1], 0.f));
    storev(&orow[c2], fmaxf(a2 + bias[c2], 0.f));
    if (t < 12) storev(&orow[c3], fmaxf(a3 + bias[c3], 0.f));
}

// ---------- cross-attention scores (one wave per node) ----------
__global__ void k_scores(const float* __restrict__ dn, const float* __restrict__ kq,
                         const float* __restrict__ qbk, const int* __restrict__ batch,
                         float* __restrict__ scores, unsigned* __restrict__ mB) {
    int wv = (blockIdx.x * blockDim.x + threadIdx.x) >> 6;
    int lane = threadIdx.x & 63;
    if (wv >= N_NODES) return;
    int b = batch[wv];
    const float* dp = dn + (size_t)wv * DOUT;
    const float* kp = kq + (size_t)b * DOUT;
    float p = dp[lane] * kp[lane] + dp[lane + 64] * kp[lane + 64];
    for (int off = 32; off > 0; off >>= 1) p += __shfl_down(p, off);
    if (lane == 0) {
        float sc = (p + qbk[b]) * 0.08838834764831845f;  // 1/sqrt(128)
        scores[wv] = sc;
        atomicMax(&mB[b], f2o(sc));
    }
}

__global__ void k_attn_e(const float* __restrict__ scores, const int* __restrict__ batch,
                         const unsigned* __restrict__ mB, float* __restrict__ enode,
                         float* __restrict__ sB) {
    int n = blockIdx.x * blockDim.x + threadIdx.x;
    if (n >= N_NODES) return;
    int b = batch[n];
    float ex = expf(scores[n] - o2f(mB[b]));
    enode[n] = ex;
    atomicAdd(&sB[b], ex);
}

// ---------- attended = dn + attn*v[batch]; segment-max pool ----------
__global__ void k_attend_pool(const float* __restrict__ dn, const float* __restrict__ vbuf,
                              const float* __restrict__ enode, const float* __restrict__ sB,
                              const int* __restrict__ batch, unsigned* __restrict__ pooled) {
    int i = blockIdx.x * blockDim.x + threadIdx.x;
    if (i >= N_NODES * 128) return;
    int n = i >> 7, t = i & 127;
    int b = batch[n];
    float attn = enode[n] / sB[b];
    float val = dn[i] + attn * vbuf[(size_t)b * 128 + t];
    atomicMax(&pooled[(size_t)b * 128 + t], f2o(val));
}

// ---------- decode pool (non-finite -> 0) + concat with pv -> bf16 ----------
__global__ void k_xc(const unsigned* __restrict__ pooled, const float* __restrict__ pv,
                     bf16* __restrict__ xcb) {
    int i = blockIdx.x * blockDim.x + threadIdx.x;
    if (i >= B_GRAPH * 384) return;
    int b = i / 384, t = i - b * 384;
    float v;
    if (t < 128) {
        v = o2f(pooled[(size_t)b * 128 + t]);
        unsigned u = __float_as_uint(v);
        if (((u >> 23) & 0xFF) == 0xFF) v = 0.f;
    } else {
        v = pv[(size_t)b * DP + (t - 128)];
    }
    xcb[i] = __float2bfloat16(v);
}

// ---------- final head ----------
__global__ void k_out(const float* __restrict__ h2, const float* __restrict__ ow,
                      const float* __restrict__ ob, float* __restrict__ out) {
    int row = (blockIdx.x * blockDim.x + threadIdx.x) >> 6;
    int lane = threadIdx.x & 63;
    if (row >= B_GRAPH) return;
    float p = 0.f;
    for (int j = lane; j < 512; j += 64) p += h2[(size_t)row * 512 + j] * ow[j];
    for (int off = 32; off > 0; off >>= 1) p += __shfl_down(p, off);
    if (lane == 0) out[row] = p + ob[0];
}

// ---------- workspace-overflow sentinel ----------
__global__ void k_fail(float* __restrict__ out, int n) {
    int i = blockIdx.x * blockDim.x + threadIdx.x;
    if (i < n) out[i] = 12345.0f;
}

extern "C" void kernel_launch(void* const* d_in, const int* in_sizes, int n_in,
                              void* d_out, int out_size, void* d_ws, size_t ws_size,
                              hipStream_t stream) {
    const float* x        = (const float*)d_in[0];
    const int*   ei       = (const int*)d_in[1];
    const int*   batch    = (const int*)d_in[2];
    const float* pvec     = (const float*)d_in[3];
    const float* pfc_w    = (const float*)d_in[4];
    const float* pfc_b    = (const float*)d_in[5];
    const float* gat_w    = (const float*)d_in[6];
    const float* gat_asrc = (const float*)d_in[7];
    const float* gat_adst = (const float*)d_in[8];
    const float* gat_b    = (const float*)d_in[9];
    const float* gcn_w    = (const float*)d_in[10];
    const float* gcn_b    = (const float*)d_in[11];
    const float* fcg1_w   = (const float*)d_in[12];
    const float* fcg1_b   = (const float*)d_in[13];
    const float* q_w      = (const float*)d_in[14];
    const float* q_b      = (const float*)d_in[15];
    const float* k_w      = (const float*)d_in[16];
    const float* k_b      = (const float*)d_in[17];
    const float* v_w      = (const float*)d_in[18];
    const float* v_b      = (const float*)d_in[19];
    const float* fc1_w    = (const float*)d_in[20];
    const float* fc1_b    = (const float*)d_in[21];
    const float* fc2_w    = (const float*)d_in[22];
    const float* fc2_b    = (const float*)d_in[23];
    const float* out_w    = (const float*)d_in[24];
    const float* out_b    = (const float*)d_in[25];
    float* out = (float*)d_out;

    // ---- workspace layout (bytes, 256-aligned) ----
    char* base = (char*)d_ws;
    size_t off = 0;
    auto alloc = [&](size_t bytes) -> void* {
        void* r = base + off;
        off += (bytes + 255) & ~(size_t)255;
        return r;
    };
    float*    pv      = (float*)alloc((size_t)B_GRAPH * DP * 4);
    bf16*     xb      = (bf16*)alloc((size_t)N_NODES * FXD * 2);
    bf16*     gat_wb  = (bf16*)alloc((size_t)FXD * HF * 2);
    bf16*     gcn_wb  = (bf16*)alloc((size_t)HF * HF * 2);
    bf16*     fcg1_wb = (bf16*)alloc((size_t)HF * DOUT * 2);
    bf16*     fc1_wb  = (bf16*)alloc((size_t)384 * 1024 * 2);
    bf16*     fc2_wb  = (bf16*)alloc((size_t)1024 * 512 * 2);
    bf16*     hB      = (bf16*)alloc((size_t)N_NODES * HF * 2);  // h, then hg
    bf16*     g1      = (bf16*)alloc((size_t)N_NODES * HF * 2);  // gat out, then gcn out
    float*    asrc    = (float*)alloc((size_t)N_NODES * H_HEADS * 4);
    float*    adst    = (float*)alloc((size_t)N_NODES * H_HEADS * 4);
    unsigned* mseg    = (unsigned*)alloc((size_t)N_NODES * H_HEADS * 4);
    float*    sseg    = (float*)alloc((size_t)N_NODES * H_HEADS * 4);
    float*    alpha   = (float*)alloc((size_t)ETOT * H_HEADS * 4);
    int*      cnt     = (int*)alloc((size_t)N_NODES * 4);
    int*      rowptr  = (int*)alloc((size_t)(N_NODES + 1) * 4);
    int*      cursor  = (int*)alloc((size_t)N_NODES * 4);
    int*      elist   = (int*)alloc((size_t)ETOT * 4);
    float*    dinv    = (float*)alloc((size_t)N_NODES * 4);
    float*    dn      = (float*)alloc((size_t)N_NODES * DOUT * 4);
    float*    kbuf    = (float*)alloc((size_t)B_GRAPH * 128 * 4);
    float*    vbuf    = (float*)alloc((size_t)B_GRAPH * 128 * 4);
    float*    kq      = (float*)alloc((size_t)B_GRAPH * 128 * 4);
    float*    qbk     = (float*)alloc((size_t)B_GRAPH * 4);
    float*    scores  = (float*)alloc((size_t)N_NODES * 4);
    float*    enode   = (float*)alloc((size_t)N_NODES * 4);
    unsigned* mB      = (unsigned*)alloc((size_t)B_GRAPH * 4);
    float*    sB      = (float*)alloc((size_t)B_GRAPH * 4);
    unsigned* pooled  = (unsigned*)alloc((size_t)B_GRAPH * 128 * 4);
    bf16*     xcb     = (bf16*)alloc((size_t)B_GRAPH * 384 * 2);
    bf16*     h1b     = (bf16*)alloc((size_t)B_GRAPH * 1024 * 2);
    float*    h2      = (float*)alloc((size_t)B_GRAPH * 512 * 4);

    if (off > ws_size) {
        k_fail<<<(out_size + 255) / 256, 256, 0, stream>>>(out, out_size);
        return;
    }

    // ---- zero accumulators ----
    (void)hipMemsetAsync(mseg, 0, (size_t)N_NODES * H_HEADS * 4, stream);
    (void)hipMemsetAsync(sseg, 0, (size_t)N_NODES * H_HEADS * 4, stream);
    (void)hipMemsetAsync(cnt, 0, (size_t)N_NODES * 4, stream);
    (void)hipMemsetAsync(mB, 0, (size_t)B_GRAPH * 4, stream);
    (void)hipMemsetAsync(sB, 0, (size_t)B_GRAPH * 4, stream);
    (void)hipMemsetAsync(pooled, 0, (size_t)B_GRAPH * 128 * 4, stream);

    // ---- bf16 conversions ----
    k_f2b<<<(N_NODES * FXD + 255) / 256, 256, 0, stream>>>(x, xb, N_NODES * FXD);
    k_f2b<<<(FXD * HF + 255) / 256, 256, 0, stream>>>(gat_w, gat_wb, FXD * HF);
    k_f2b<<<(HF * HF + 255) / 256, 256, 0, stream>>>(gcn_w, gcn_wb, HF * HF);
    k_f2b<<<(HF * DOUT + 255) / 256, 256, 0, stream>>>(fcg1_w, fcg1_wb, HF * DOUT);
    k_f2b<<<(384 * 1024 + 255) / 256, 256, 0, stream>>>(fc1_w, fc1_wb, 384 * 1024);
    k_f2b<<<(1024 * 512 + 255) / 256, 256, 0, stream>>>(fc2_w, fc2_wb, 1024 * 512);

    // ---- protein path ----
    k_pv<<<B_GRAPH, 256, 0, stream>>>(pvec, pfc_w, pfc_b, pv);
    k_kv<<<B_GRAPH, 256, 0, stream>>>(pv, k_w, k_b, v_w, v_b, kbuf, vbuf);
    k_kq<<<B_GRAPH, 128, 0, stream>>>(q_w, q_b, kbuf, kq, qbk);

    // ---- CSR build ----
    k_count<<<(ETOT + 255) / 256, 256, 0, stream>>>(ei, cnt);
    k_scan<<<1, 1024, 0, stream>>>(cnt, rowptr, cursor);
    k_scatter<<<(ETOT + 255) / 256, 256, 0, stream>>>(ei, cursor, elist);
    k_dinv<<<(N_NODES + 255) / 256, 256, 0, stream>>>(cnt, dinv);

    // ---- GAT ----
    mfma_mm<bf16, 0, 0><<<mm_grid(N_NODES, HF), 256, 0, stream>>>(
        (const ushort*)xb, (const ushort*)gat_wb, nullptr, hB, N_NODES, FXD, HF);
    k_att<<<(N_NODES * H_HEADS + 255) / 256, 256, 0, stream>>>(hB, gat_asrc, gat_adst,
                                                               asrc, adst);
    k_alpha_max<<<(ETOT * H_HEADS + 255) / 256, 256, 0, stream>>>(ei, asrc, adst, alpha, mseg);
    k_exp_sum<<<(ETOT * H_HEADS + 255) / 256, 256, 0, stream>>>(ei, alpha, mseg, sseg);
    k_gat_aggr_csr<<<N_NODES, 256, 0, stream>>>(rowptr, elist, ei, hB, alpha, sseg, gat_b, g1);

    // ---- GCN ----
    mfma_mm<bf16, 0, 0><<<mm_grid(N_NODES, HF), 256, 0, stream>>>(
        (const ushort*)g1, (const ushort*)gcn_wb, nullptr, hB, N_NODES, HF, HF);
    k_gcn_aggr_csr<<<N_NODES, 256, 0, stream>>>(rowptr, elist, ei, hB, dinv, gcn_b, g1);

    // ---- fc_g1 (bf16 MFMA, fp32 out, bias+relu) ----
    mfma_mm<float, 1, 1><<<mm_grid(N_NODES, DOUT), 256, 0, stream>>>(
        (const ushort*)g1, (const ushort*)fcg1_wb, fcg1_b, dn, N_NODES, HF, DOUT);

    // ---- cross attention + pool ----
    k_scores<<<(N_NODES * 64 + 255) / 256, 256, 0, stream>>>(dn, kq, qbk, batch, scores, mB);
    k_attn_e<<<(N_NODES + 255) / 256, 256, 0, stream>>>(scores, batch, mB, enode, sB);
    k_attend_pool<<<(N_NODES * 128 + 255) / 256, 256, 0, stream>>>(dn, vbuf, enode,
                                                                   sB, batch, pooled);
    k_xc<<<(B_GRAPH * 384 + 255) / 256, 256, 0, stream>>>(pooled, pv, xcb);

    // ---- head MLP (bf16 MFMA) ----
    mfma_mm<bf16, 1, 1><<<mm_grid(B_GRAPH, 1024), 256, 0, stream>>>(
        (const ushort*)xcb, (const ushort*)fc1_wb, fc1_b, h1b, B_GRAPH, 384, 1024);
    mfma_mm<float, 1, 1><<<mm_grid(B_GRAPH, 512), 256, 0, stream>>>(
        (const ushort*)h1b, (const ushort*)fc2_wb, fc2_b, h2, B_GRAPH, 1024, 512);
    k_out<<<(B_GRAPH * 64 + 255) / 256, 256, 0, stream>>>(h2, out_w, out_b, out);
}

// Round 7
// 845.756 us; speedup vs baseline: 1.3119x; 1.3119x over previous
//
#include <hip/hip_runtime.h>
#include <hip/hip_bf16.h>
#include <math.h>

#define N_NODES 40000
#define E_EDGES 160000
#define ETOT    (E_EDGES + N_NODES)   // 200000 (with self-loops)
#define B_GRAPH 1024
#define FXD     78
#define H_HEADS 10
#define HF      (H_HEADS * FXD)       // 780
#define HF_LD   800                   // padded leading dim for GEMM-A buffers
#define XK_LD   96                    // padded K for x (78 -> 96)
#define DOUT    128
#define DP      256

typedef __hip_bfloat16 bf16;
typedef __attribute__((ext_vector_type(8))) short short8;
typedef __attribute__((ext_vector_type(4))) float f32x4;

// ---------- ordered-float encoding for atomic max on unsigned ----------
static __device__ __forceinline__ unsigned f2o(float f) {
    unsigned u = __float_as_uint(f);
    return (u & 0x80000000u) ? ~u : (u | 0x80000000u);
}
static __device__ __forceinline__ float o2f(unsigned o) {
    unsigned u = (o & 0x80000000u) ? (o & 0x7FFFFFFFu) : ~o;
    return __uint_as_float(u);
}

static __device__ __forceinline__ void storev(float* p, float v) { *p = v; }
static __device__ __forceinline__ void storev(bf16* p, float v) { *p = __float2bfloat16(v); }
static __device__ __forceinline__ float loadv(const float* p) { return *p; }
static __device__ __forceinline__ float loadv(const bf16* p) { return __bfloat162float(*p); }

// edge e -> (src, dst); e >= E_EDGES are self-loops
static __device__ __forceinline__ void edge_sd(const int* __restrict__ ei, int e, int& s, int& d) {
    if (e < E_EDGES) { s = ei[e]; d = ei[E_EDGES + e]; }
    else             { s = e - E_EDGES; d = s; }
}

// ---------- fp32 -> bf16 convert (row-padded) ----------
__global__ void k_f2b_pad(const float* __restrict__ in, bf16* __restrict__ out,
                          int M, int K, int ldk) {
    int i = blockIdx.x * blockDim.x + threadIdx.x;
    if (i >= M * ldk) return;
    int r = i / ldk, k = i - r * ldk;
    out[i] = __float2bfloat16((k < K) ? in[(size_t)r * K + k] : 0.f);
}

// ---------- fp32 W[K][N] -> bf16 WT[N][ldk] (transposed, K zero-padded) ----------
__global__ void k_f2bt(const float* __restrict__ w, bf16* __restrict__ wt,
                       int K, int N, int ldk) {
    int i = blockIdx.x * blockDim.x + threadIdx.x;
    if (i >= N * ldk) return;
    int n = i / ldk, k = i - n * ldk;
    wt[i] = __float2bfloat16((k < K) ? w[(size_t)k * N + n] : 0.f);
}

// ---------- MFMA bf16 GEMM: C[M,N] = A[M,K] @ WT[N,K]^T (+bias)(+relu) ----------
// BM=128, BN=128, BK=32; 256 threads = 4 waves, wave w -> rows [w*32, w*32+32).
// Requires K % 32 == 0, lda/ldb % 8 == 0 (pads are zero in WT so they add 0).
// All staging is 16B global loads -> 16B ds_write_b128 (R6 post-mortem: scalar
// ds_write_u16 staging made the kernel LDS-issue-bound at MfmaUtil 8%).
// 1-D grid, XCD-grouped swizzle (all col-tiles of a row-tile share p%8 -> same
// XCD L2; R6: FETCH dropped 774->45MB).
template <typename OutT, int BIAS, int RELU>
__global__ __launch_bounds__(256)
void mfma_mm(const ushort* __restrict__ A, int lda, const ushort* __restrict__ WT, int ldb,
             const float* __restrict__ bias, OutT* __restrict__ C,
             int M, int K, int N) {
    const int RT = (M + 127) >> 7;
    const int CT = (N + 127) >> 7;
    const int p = blockIdx.x;
    const int r = (p & 7) + 8 * (p / (8 * CT));
    const int c = (p >> 3) % CT;
    if (r >= RT) return;
    const int m0 = r * 128;
    const int n0 = c * 128;

    __shared__ ushort As[128 * 40];   // row stride 40 elems (80B, 16B-aligned)
    __shared__ ushort Bs[128 * 40];   // Bs[n][k]
    const int tid = threadIdx.x;
    const int wave = tid >> 6, lane = tid & 63;
    const int quad = lane >> 4, l16 = lane & 15;

    f32x4 acc[2][8];
#pragma unroll
    for (int mi = 0; mi < 2; mi++)
#pragma unroll
        for (int ni = 0; ni < 8; ni++) acc[mi][ni] = (f32x4){0.f, 0.f, 0.f, 0.f};

    const int ar = tid >> 1;            // staged row 0..127 (for both A and B tiles)
    const int ak = (tid & 1) * 16;      // k offset 0/16

    int grow = m0 + ar; if (grow >= M) grow = M - 1;  // clamp; garbage discarded in epilogue
    int gn   = n0 + ar; if (gn >= N)   gn = N - 1;
    const ushort* arow = A  + (size_t)grow * lda + ak;
    const ushort* brow = WT + (size_t)gn * ldb + ak;

    for (int kb = 0; kb < K; kb += 32) {
        uint4 a0 = *(const uint4*)(arow + kb);
        uint4 a1 = *(const uint4*)(arow + kb + 8);
        uint4 b0 = *(const uint4*)(brow + kb);
        uint4 b1 = *(const uint4*)(brow + kb + 8);
        *(uint4*)&As[ar * 40 + ak]     = a0;
        *(uint4*)&As[ar * 40 + ak + 8] = a1;
        *(uint4*)&Bs[ar * 40 + ak]     = b0;
        *(uint4*)&Bs[ar * 40 + ak + 8] = b1;
        __syncthreads();
        // ---- compute: 2x8 grid of 16x16x32 mfma ----
        const int wr = wave * 32;
        short8 af[2], bfr[8];
        af[0] = *(const short8*)&As[(wr + l16) * 40 + quad * 8];
        af[1] = *(const short8*)&As[(wr + 16 + l16) * 40 + quad * 8];
#pragma unroll
        for (int ni = 0; ni < 8; ni++)
            bfr[ni] = *(const short8*)&Bs[(ni * 16 + l16) * 40 + quad * 8];
#pragma unroll
        for (int mi = 0; mi < 2; mi++)
#pragma unroll
            for (int ni = 0; ni < 8; ni++)
                acc[mi][ni] = __builtin_amdgcn_mfma_f32_16x16x32_bf16(
                    af[mi], bfr[ni], acc[mi][ni], 0, 0, 0);
        __syncthreads();
    }
    // ---- epilogue: C row = quad*4+reg, col = lane&15 ----
#pragma unroll
    for (int mi = 0; mi < 2; mi++)
#pragma unroll
        for (int ni = 0; ni < 8; ni++)
#pragma unroll
            for (int rg = 0; rg < 4; rg++) {
                int row = m0 + wave * 32 + mi * 16 + quad * 4 + rg;
                int col = n0 + ni * 16 + l16;
                if (row < M && col < N) {
                    float v = acc[mi][ni][rg];
                    if (BIAS) v += bias[col];
                    if (RELU) v = fmaxf(v, 0.f);
                    storev(&C[(size_t)row * N + col], v);
                }
            }
}

static inline int mm_grid(int M, int N) {
    int RT = (M + 127) >> 7, CT = (N + 127) >> 7;
    int RTpad = ((RT + 7) >> 3) << 3;
    return RTpad * CT;
}

// ---------- protein fc ----------
__global__ void k_pv(const float* __restrict__ pvec, const float* __restrict__ w,
                     const float* __restrict__ b, float* __restrict__ pv) {
    __shared__ float sm[DP];
    int bg = blockIdx.x, t = threadIdx.x;
    sm[t] = pvec[(size_t)bg * DP + t];
    __syncthreads();
    float acc = 0.f;
    for (int k = 0; k < DP; k++) acc += sm[k] * w[(size_t)k * DP + t];
    pv[(size_t)bg * DP + t] = fmaxf(acc + b[t], 0.f);
}

// ---------- k/v projections ----------
__global__ void k_kv(const float* __restrict__ pv,
                     const float* __restrict__ kw, const float* __restrict__ kb,
                     const float* __restrict__ vw, const float* __restrict__ vb,
                     float* __restrict__ kbuf, float* __restrict__ vbuf) {
    __shared__ float sm[DP];
    int bg = blockIdx.x, t = threadIdx.x;
    sm[t] = pv[(size_t)bg * DP + t];
    __syncthreads();
    int o = t & 127;
    const float* w = (t < 128) ? kw : vw;
    const float* bb = (t < 128) ? kb : vb;
    float acc = 0.f;
    for (int k = 0; k < DP; k++) acc += sm[k] * w[(size_t)k * 128 + o];
    float v = acc + bb[o];
    if (t < 128) kbuf[(size_t)bg * 128 + o] = v;
    else         vbuf[(size_t)bg * 128 + o] = v;
}

// ---------- kq[b,k] = q_w @ k[b]; qbk[b] = q_b . k[b] ----------
__global__ void k_kq(const float* __restrict__ qw, const float* __restrict__ qb,
                     const float* __restrict__ kbuf, float* __restrict__ kq,
                     float* __restrict__ qbk) {
    __shared__ float kb[128];
    int b = blockIdx.x, t = threadIdx.x;  // 128 threads
    kb[t] = kbuf[(size_t)b * 128 + t];
    __syncthreads();
    float acc = 0.f;
    for (int o = 0; o < 128; o++) acc += qw[(size_t)t * 128 + o] * kb[o];
    kq[(size_t)b * 128 + t] = acc;
    if (t == 0) {
        float s = 0.f;
        for (int o = 0; o < 128; o++) s += qb[o] * kb[o];
        qbk[b] = s;
    }
}

// ---------- GAT per-node attention logits ----------
__global__ void k_att(const bf16* __restrict__ h, const float* __restrict__ aw_s,
                      const float* __restrict__ aw_d, float* __restrict__ asrc,
                      float* __restrict__ adst) {
    int i = blockIdx.x * blockDim.x + threadIdx.x;
    if (i >= N_NODES * H_HEADS) return;
    int n = i / H_HEADS, hh = i - n * H_HEADS;
    const bf16* hp = h + (size_t)n * HF + hh * FXD;
    const float* ws = aw_s + hh * FXD;
    const float* wd = aw_d + hh * FXD;
    float s1 = 0.f, s2 = 0.f;
    for (int c = 0; c < FXD; c++) { float v = loadv(&hp[c]); s1 += v * ws[c]; s2 += v * wd[c]; }
    asrc[i] = s1; adst[i] = s2;
}

// ---------- edge alpha + segment max over dst ----------
__global__ void k_alpha_max(const int* __restrict__ ei, const float* __restrict__ asrc,
                            const float* __restrict__ adst, float* __restrict__ alpha,
                            unsigned* __restrict__ mseg) {
    int i = blockIdx.x * blockDim.x + threadIdx.x;
    if (i >= ETOT * H_HEADS) return;
    int e = i / H_HEADS, hh = i - e * H_HEADS;
    int s, d; edge_sd(ei, e, s, d);
    float a = asrc[(size_t)s * H_HEADS + hh] + adst[(size_t)d * H_HEADS + hh];
    a = (a >= 0.f) ? a : 0.2f * a;
    alpha[i] = a;
    atomicMax(&mseg[(size_t)d * H_HEADS + hh], f2o(a));
}

// ---------- exp(alpha - m[dst]) in place + segment sum ----------
__global__ void k_exp_sum(const int* __restrict__ ei, float* __restrict__ alpha,
                          const unsigned* __restrict__ mseg, float* __restrict__ sseg) {
    int i = blockIdx.x * blockDim.x + threadIdx.x;
    if (i >= ETOT * H_HEADS) return;
    int e = i / H_HEADS, hh = i - e * H_HEADS;
    int s, d; edge_sd(ei, e, s, d);
    (void)s;
    float ex = expf(alpha[i] - o2f(mseg[(size_t)d * H_HEADS + hh]));
    alpha[i] = ex;
    atomicAdd(&sseg[(size_t)d * H_HEADS + hh], ex);
}

// ---------- CSR build: count, scan, scatter ----------
__global__ void k_count(const int* __restrict__ ei, int* __restrict__ cnt) {
    int e = blockIdx.x * blockDim.x + threadIdx.x;
    if (e >= ETOT) return;
    int d = (e < E_EDGES) ? ei[E_EDGES + e] : e - E_EDGES;
    atomicAdd(&cnt[d], 1);
}

__global__ void k_scan(const int* __restrict__ cnt, int* __restrict__ rowptr,
                       int* __restrict__ cursor) {  // 1 block, 1024 threads
    __shared__ int ps[1024];
    const int t = threadIdx.x;
    const int CH = 40;  // 1024*40 = 40960 >= 40000
    int base = t * CH;
    int s = 0;
    for (int i = 0; i < CH; i++) {
        int idx = base + i;
        if (idx < N_NODES) s += cnt[idx];
    }
    ps[t] = s;
    __syncthreads();
    for (int off = 1; off < 1024; off <<= 1) {
        int v = (t >= off) ? ps[t - off] : 0;
        __syncthreads();
        ps[t] += v;
        __syncthreads();
    }
    int run = (t == 0) ? 0 : ps[t - 1];
    for (int i = 0; i < CH; i++) {
        int idx = base + i;
        if (idx < N_NODES) {
            rowptr[idx] = run;
            cursor[idx] = run;
            run += cnt[idx];
        }
    }
    if (t == 1023) rowptr[N_NODES] = ps[1023];
}

__global__ void k_scatter(const int* __restrict__ ei, int* __restrict__ cursor,
                          int* __restrict__ elist) {
    int e = blockIdx.x * blockDim.x + threadIdx.x;
    if (e >= ETOT) return;
    int d = (e < E_EDGES) ? ei[E_EDGES + e] : e - E_EDGES;
    int pos = atomicAdd(&cursor[d], 1);
    elist[pos] = e;
}

__global__ void k_dinv(const int* __restrict__ cnt, float* __restrict__ dinv) {
    int n = blockIdx.x * blockDim.x + threadIdx.x;
    if (n >= N_NODES) return;
    int c = cnt[n];
    dinv[n] = (c > 0) ? 1.0f / sqrtf((float)c) : 0.f;
}

// ---------- GAT aggregation (CSR) + fused bias+relu -> bf16 (ld-strided out) ----------
__global__ __launch_bounds__(256)
void k_gat_aggr_csr(const int* __restrict__ rowptr, const int* __restrict__ elist,
                    const int* __restrict__ ei, const bf16* __restrict__ h,
                    const float* __restrict__ eexp, const float* __restrict__ sseg,
                    const float* __restrict__ bias, bf16* __restrict__ outb) {
    __shared__ float sinv[H_HEADS];
    int d = blockIdx.x, t = threadIdx.x;
    if (t < H_HEADS) sinv[t] = 1.f / (sseg[(size_t)d * H_HEADS + t] + 1e-16f);
    __syncthreads();
    int beg = rowptr[d], end = rowptr[d + 1];
    const int c0 = t, c1 = t + 256, c2 = t + 512, c3 = 768 + t;  // c3 valid if t<12
    const int h0 = c0 / FXD, h1 = c1 / FXD, h2 = c2 / FXD;       // h3 == 9
    float a0 = 0.f, a1 = 0.f, a2 = 0.f, a3 = 0.f;
    for (int i = beg; i < end; i++) {
        int e = elist[i];
        int s, dd; edge_sd(ei, e, s, dd);
        const float* ex = eexp + (size_t)e * H_HEADS;
        const bf16* hr = h + (size_t)s * HF;
        a0 += ex[h0] * loadv(&hr[c0]);
        a1 += ex[h1] * loadv(&hr[c1]);
        a2 += ex[h2] * loadv(&hr[c2]);
        if (t < 12) a3 += ex[9] * loadv(&hr[c3]);
    }
    bf16* orow = outb + (size_t)d * HF_LD;
    storev(&orow[c0], fmaxf(a0 * sinv[h0] + bias[c0], 0.f));
    storev(&orow[c1], fmaxf(a1 * sinv[h1] + bias[c1], 0.f));
    storev(&orow[c2], fmaxf(a2 * sinv[h2] + bias[c2], 0.f));
    if (t < 12) storev(&orow[c3], fmaxf(a3 * sinv[9] + bias[c3], 0.f));
}

// ---------- GCN aggregation (CSR) + fused bias+relu -> bf16 (ld-strided out) ----------
__global__ __launch_bounds__(256)
void k_gcn_aggr_csr(const int* __restrict__ rowptr, const int* __restrict__ elist,
                    const int* __restrict__ ei, const bf16* __restrict__ hg,
                    const float* __restrict__ dinv, const float* __restrict__ bias,
                    bf16* __restrict__ outb) {
    int d = blockIdx.x, t = threadIdx.x;
    float dv = dinv[d];
    int beg = rowptr[d], end = rowptr[d + 1];
    const int c0 = t, c1 = t + 256, c2 = t + 512, c3 = 768 + t;
    float a0 = 0.f, a1 = 0.f, a2 = 0.f, a3 = 0.f;
    for (int i = beg; i < end; i++) {
        int e = elist[i];
        int s, dd; edge_sd(ei, e, s, dd);
        float w = dinv[s] * dv;
        const bf16* hr = hg + (size_t)s * HF;
        a0 += w * loadv(&hr[c0]);
        a1 += w * loadv(&hr[c1]);
        a2 += w * loadv(&hr[c2]);
        if (t < 12) a3 += w * loadv(&hr[c3]);
    }
    bf16* orow = outb + (size_t)d * HF_LD;
    storev(&orow[c0], fmaxf(a0 + bias[c0], 0.f));
    storev(&orow[c1], fmaxf(a1 + bias[c1], 0.f));
    storev(&orow[c2], fmaxf(a2 + bias[c2], 0.f));
    if (t < 12) storev(&orow[c3], fmaxf(a3 + bias[c3], 0.f));
}

// ---------- cross-attention scores (one wave per node) ----------
__global__ void k_scores(const float* __restrict__ dn, const float* __restrict__ kq,
                         const float* __restrict__ qbk, const int* __restrict__ batch,
                         float* __restrict__ scores, unsigned* __restrict__ mB) {
    int wv = (blockIdx.x * blockDim.x + threadIdx.x) >> 6;
    int lane = threadIdx.x & 63;
    if (wv >= N_NODES) return;
    int b = batch[wv];
    const float* dp = dn + (size_t)wv * DOUT;
    const float* kp = kq + (size_t)b * DOUT;
    float p = dp[lane] * kp[lane] + dp[lane + 64] * kp[lane + 64];
    for (int off = 32; off > 0; off >>= 1) p += __shfl_down(p, off);
    if (lane == 0) {
        float sc = (p + qbk[b]) * 0.08838834764831845f;  // 1/sqrt(128)
        scores[wv] = sc;
        atomicMax(&mB[b], f2o(sc));
    }
}

__global__ void k_attn_e(const float* __restrict__ scores, const int* __restrict__ batch,
                         const unsigned* __restrict__ mB, float* __restrict__ enode,
                         float* __restrict__ sB) {
    int n = blockIdx.x * blockDim.x + threadIdx.x;
    if (n >= N_NODES) return;
    int b = batch[n];
    float ex = expf(scores[n] - o2f(mB[b]));
    enode[n] = ex;
    atomicAdd(&sB[b], ex);
}

// ---------- attended = dn + attn*v[batch]; segment-max pool ----------
__global__ void k_attend_pool(const float* __restrict__ dn, const float* __restrict__ vbuf,
                              const float* __restrict__ enode, const float* __restrict__ sB,
                              const int* __restrict__ batch, unsigned* __restrict__ pooled) {
    int i = blockIdx.x * blockDim.x + threadIdx.x;
    if (i >= N_NODES * 128) return;
    int n = i >> 7, t = i & 127;
    int b = batch[n];
    float attn = enode[n] / sB[b];
    float val = dn[i] + attn * vbuf[(size_t)b * 128 + t];
    atomicMax(&pooled[(size_t)b * 128 + t], f2o(val));
}

// ---------- decode pool (non-finite -> 0) + concat with pv -> bf16 ----------
__global__ void k_xc(const unsigned* __restrict__ pooled, const float* __restrict__ pv,
                     bf16* __restrict__ xcb) {
    int i = blockIdx.x * blockDim.x + threadIdx.x;
    if (i >= B_GRAPH * 384) return;
    int b = i / 384, t = i - b * 384;
    float v;
    if (t < 128) {
        v = o2f(pooled[(size_t)b * 128 + t]);
        unsigned u = __float_as_uint(v);
        if (((u >> 23) & 0xFF) == 0xFF) v = 0.f;
    } else {
        v = pv[(size_t)b * DP + (t - 128)];
    }
    xcb[i] = __float2bfloat16(v);
}

// ---------- final head ----------
__global__ void k_out(const float* __restrict__ h2, const float* __restrict__ ow,
                      const float* __restrict__ ob, float* __restrict__ out) {
    int row = (blockIdx.x * blockDim.x + threadIdx.x) >> 6;
    int lane = threadIdx.x & 63;
    if (row >= B_GRAPH) return;
    float p = 0.f;
    for (int j = lane; j < 512; j += 64) p += h2[(size_t)row * 512 + j] * ow[j];
    for (int off = 32; off > 0; off >>= 1) p += __shfl_down(p, off);
    if (lane == 0) out[row] = p + ob[0];
}

// ---------- workspace-overflow sentinel ----------
__global__ void k_fail(float* __restrict__ out, int n) {
    int i = blockIdx.x * blockDim.x + threadIdx.x;
    if (i < n) out[i] = 12345.0f;
}

extern "C" void kernel_launch(void* const* d_in, const int* in_sizes, int n_in,
                              void* d_out, int out_size, void* d_ws, size_t ws_size,
                              hipStream_t stream) {
    const float* x        = (const float*)d_in[0];
    const int*   ei       = (const int*)d_in[1];
    const int*   batch    = (const int*)d_in[2];
    const float* pvec     = (const float*)d_in[3];
    const float* pfc_w    = (const float*)d_in[4];
    const float* pfc_b    = (const float*)d_in[5];
    const float* gat_w    = (const float*)d_in[6];
    const float* gat_asrc = (const float*)d_in[7];
    const float* gat_adst = (const float*)d_in[8];
    const float* gat_b    = (const float*)d_in[9];
    const float* gcn_w    = (const float*)d_in[10];
    const float* gcn_b    = (const float*)d_in[11];
    const float* fcg1_w   = (const float*)d_in[12];
    const float* fcg1_b   = (const float*)d_in[13];
    const float* q_w      = (const float*)d_in[14];
    const float* q_b      = (const float*)d_in[15];
    const float* k_w      = (const float*)d_in[16];
    const float* k_b      = (const float*)d_in[17];
    const float* v_w      = (const float*)d_in[18];
    const float* v_b      = (const float*)d_in[19];
    const float* fc1_w    = (const float*)d_in[20];
    const float* fc1_b    = (const float*)d_in[21];
    const float* fc2_w    = (const float*)d_in[22];
    const float* fc2_b    = (const float*)d_in[23];
    const float* out_w    = (const float*)d_in[24];
    const float* out_b    = (const float*)d_in[25];
    float* out = (float*)d_out;

    // ---- workspace layout (bytes, 256-aligned) ----
    char* base = (char*)d_ws;
    size_t off = 0;
    auto alloc = [&](size_t bytes) -> void* {
        void* r = base + off;
        off += (bytes + 255) & ~(size_t)255;
        return r;
    };
    float*    pv      = (float*)alloc((size_t)B_GRAPH * DP * 4);
    bf16*     xb      = (bf16*)alloc((size_t)N_NODES * XK_LD * 2);     // x, K-padded
    bf16*     wt_gat  = (bf16*)alloc((size_t)HF * XK_LD * 2);          // [780][96]
    bf16*     wt_gcn  = (bf16*)alloc((size_t)HF * HF_LD * 2);          // [780][800]
    bf16*     wt_fcg1 = (bf16*)alloc((size_t)DOUT * HF_LD * 2);        // [128][800]
    bf16*     wt_fc1  = (bf16*)alloc((size_t)1024 * 384 * 2);          // [1024][384]
    bf16*     wt_fc2  = (bf16*)alloc((size_t)512 * 1024 * 2);          // [512][1024]
    bf16*     hB      = (bf16*)alloc((size_t)N_NODES * HF * 2);        // h, then hg (ld HF)
    bf16*     g1      = (bf16*)alloc((size_t)N_NODES * HF_LD * 2);     // aggr outs (ld 800)
    float*    asrc    = (float*)alloc((size_t)N_NODES * H_HEADS * 4);
    float*    adst    = (float*)alloc((size_t)N_NODES * H_HEADS * 4);
    unsigned* mseg    = (unsigned*)alloc((size_t)N_NODES * H_HEADS * 4);
    float*    sseg    = (float*)alloc((size_t)N_NODES * H_HEADS * 4);
    float*    alpha   = (float*)alloc((size_t)ETOT * H_HEADS * 4);
    int*      cnt     = (int*)alloc((size_t)N_NODES * 4);
    int*      rowptr  = (int*)alloc((size_t)(N_NODES + 1) * 4);
    int*      cursor  = (int*)alloc((size_t)N_NODES * 4);
    int*      elist   = (int*)alloc((size_t)ETOT * 4);
    float*    dinv    = (float*)alloc((size_t)N_NODES * 4);
    float*    dn      = (float*)alloc((size_t)N_NODES * DOUT * 4);
    float*    kbuf    = (float*)alloc((size_t)B_GRAPH * 128 * 4);
    float*    vbuf    = (float*)alloc((size_t)B_GRAPH * 128 * 4);
    float*    kq      = (float*)alloc((size_t)B_GRAPH * 128 * 4);
    float*    qbk     = (float*)alloc((size_t)B_GRAPH * 4);
    float*    scores  = (float*)alloc((size_t)N_NODES * 4);
    float*    enode   = (float*)alloc((size_t)N_NODES * 4);
    unsigned* mB      = (unsigned*)alloc((size_t)B_GRAPH * 4);
    float*    sB      = (float*)alloc((size_t)B_GRAPH * 4);
    unsigned* pooled  = (unsigned*)alloc((size_t)B_GRAPH * 128 * 4);
    bf16*     xcb     = (bf16*)alloc((size_t)B_GRAPH * 384 * 2);
    bf16*     h1b     = (bf16*)alloc((size_t)B_GRAPH * 1024 * 2);
    float*    h2      = (float*)alloc((size_t)B_GRAPH * 512 * 4);

    if (off > ws_size) {
        k_fail<<<(out_size + 255) / 256, 256, 0, stream>>>(out, out_size);
        return;
    }

    // ---- zero accumulators ----
    (void)hipMemsetAsync(mseg, 0, (size_t)N_NODES * H_HEADS * 4, stream);
    (void)hipMemsetAsync(sseg, 0, (size_t)N_NODES * H_HEADS * 4, stream);
    (void)hipMemsetAsync(cnt, 0, (size_t)N_NODES * 4, stream);
    (void)hipMemsetAsync(mB, 0, (size_t)B_GRAPH * 4, stream);
    (void)hipMemsetAsync(sB, 0, (size_t)B_GRAPH * 4, stream);
    (void)hipMemsetAsync(pooled, 0, (size_t)B_GRAPH * 128 * 4, stream);

    // ---- bf16 conversions / weight transposes ----
    k_f2b_pad<<<(N_NODES * XK_LD + 255) / 256, 256, 0, stream>>>(x, xb, N_NODES, FXD, XK_LD);
    k_f2bt<<<(HF * XK_LD + 255) / 256, 256, 0, stream>>>(gat_w, wt_gat, FXD, HF, XK_LD);
    k_f2bt<<<(HF * HF_LD + 255) / 256, 256, 0, stream>>>(gcn_w, wt_gcn, HF, HF, HF_LD);
    k_f2bt<<<(DOUT * HF_LD + 255) / 256, 256, 0, stream>>>(fcg1_w, wt_fcg1, HF, DOUT, HF_LD);
    k_f2bt<<<(1024 * 384 + 255) / 256, 256, 0, stream>>>(fc1_w, wt_fc1, 384, 1024, 384);
    k_f2bt<<<(512 * 1024 + 255) / 256, 256, 0, stream>>>(fc2_w, wt_fc2, 1024, 512, 1024);

    // ---- protein path ----
    k_pv<<<B_GRAPH, 256, 0, stream>>>(pvec, pfc_w, pfc_b, pv);
    k_kv<<<B_GRAPH, 256, 0, stream>>>(pv, k_w, k_b, v_w, v_b, kbuf, vbuf);
    k_kq<<<B_GRAPH, 128, 0, stream>>>(q_w, q_b, kbuf, kq, qbk);

    // ---- CSR build ----
    k_count<<<(ETOT + 255) / 256, 256, 0, stream>>>(ei, cnt);
    k_scan<<<1, 1024, 0, stream>>>(cnt, rowptr, cursor);
    k_scatter<<<(ETOT + 255) / 256, 256, 0, stream>>>(ei, cursor, elist);
    k_dinv<<<(N_NODES + 255) / 256, 256, 0, stream>>>(cnt, dinv);

    // ---- GAT ----
    mfma_mm<bf16, 0, 0><<<mm_grid(N_NODES, HF), 256, 0, stream>>>(
        (const ushort*)xb, XK_LD, (const ushort*)wt_gat, XK_LD, nullptr, hB,
        N_NODES, XK_LD, HF);
    k_att<<<(N_NODES * H_HEADS + 255) / 256, 256, 0, stream>>>(hB, gat_asrc, gat_adst,
                                                               asrc, adst);
    k_alpha_max<<<(ETOT * H_HEADS + 255) / 256, 256, 0, stream>>>(ei, asrc, adst, alpha, mseg);
    k_exp_sum<<<(ETOT * H_HEADS + 255) / 256, 256, 0, stream>>>(ei, alpha, mseg, sseg);
    k_gat_aggr_csr<<<N_NODES, 256, 0, stream>>>(rowptr, elist, ei, hB, alpha, sseg, gat_b, g1);

    // ---- GCN ----
    mfma_mm<bf16, 0, 0><<<mm_grid(N_NODES, HF), 256, 0, stream>>>(
        (const ushort*)g1, HF_LD, (const ushort*)wt_gcn, HF_LD, nullptr, hB,
        N_NODES, HF_LD, HF);
    k_gcn_aggr_csr<<<N_NODES, 256, 0, stream>>>(rowptr, elist, ei, hB, dinv, gcn_b, g1);

    // ---- fc_g1 (bf16 MFMA, fp32 out, bias+relu) ----
    mfma_mm<float, 1, 1><<<mm_grid(N_NODES, DOUT), 256, 0, stream>>>(
        (const ushort*)g1, HF_LD, (const ushort*)wt_fcg1, HF_LD, fcg1_b, dn,
        N_NODES, HF_LD, DOUT);

    // ---- cross attention + pool ----
    k_scores<<<(N_NODES * 64 + 255) / 256, 256, 0, stream>>>(dn, kq, qbk, batch, scores, mB);
    k_attn_e<<<(N_NODES + 255) / 256, 256, 0, stream>>>(scores, batch, mB, enode, sB);
    k_attend_pool<<<(N_NODES * 128 + 255) / 256, 256, 0, stream>>>(dn, vbuf, enode,
                                                                   sB, batch, pooled);
    k_xc<<<(B_GRAPH * 384 + 255) / 256, 256, 0, stream>>>(pooled, pv, xcb);

    // ---- head MLP (bf16 MFMA) ----
    mfma_mm<bf16, 1, 1><<<mm_grid(B_GRAPH, 1024), 256, 0, stream>>>(
        (const ushort*)xcb, 384, (const ushort*)wt_fc1, 384, fc1_b, h1b,
        B_GRAPH, 384, 1024);
    mfma_mm<float, 1, 1><<<mm_grid(B_GRAPH, 512), 256, 0, stream>>>(
        (const ushort*)h1b, 1024, (const ushort*)wt_fc2, 1024, fc2_b, h2,
        B_GRAPH, 1024, 512);
    k_out<<<(B_GRAPH * 64 + 255) / 256, 256, 0, stream>>>(h2, out_w, out_b, out);
}

// Round 8
// 799.056 us; speedup vs baseline: 1.3886x; 1.0584x over previous
//
#include <hip/hip_runtime.h>
#include <hip/hip_bf16.h>
#include <math.h>

#define N_NODES 40000
#define E_EDGES 160000
#define ETOT    (E_EDGES + N_NODES)   // 200000 (with self-loops)
#define B_GRAPH 1024
#define FXD     78
#define H_HEADS 10
#define HF      (H_HEADS * FXD)       // 780
#define HF_LD   800                   // padded leading dim (16B-aligned rows)
#define XK_LD   96                    // padded K for x (78 -> 96)
#define DOUT    128
#define DP      256

typedef __hip_bfloat16 bf16;
typedef __attribute__((ext_vector_type(8))) short short8;
typedef __attribute__((ext_vector_type(4))) float f32x4;

// ---------- ordered-float encoding for atomic max on unsigned ----------
static __device__ __forceinline__ unsigned f2o(float f) {
    unsigned u = __float_as_uint(f);
    return (u & 0x80000000u) ? ~u : (u | 0x80000000u);
}
static __device__ __forceinline__ float o2f(unsigned o) {
    unsigned u = (o & 0x80000000u) ? (o & 0x7FFFFFFFu) : ~o;
    return __uint_as_float(u);
}

static __device__ __forceinline__ void storev(float* p, float v) { *p = v; }
static __device__ __forceinline__ void storev(bf16* p, float v) { *p = __float2bfloat16(v); }
static __device__ __forceinline__ float loadv(const float* p) { return *p; }
static __device__ __forceinline__ float loadv(const bf16* p) { return __bfloat162float(*p); }

static __device__ __forceinline__ ushort f2b_bits(float v) {
    bf16 b = __float2bfloat16(v);
    return *reinterpret_cast<ushort*>(&b);
}
static __device__ __forceinline__ float b2f_bits(short u) {
    return __uint_as_float(((unsigned)(unsigned short)u) << 16);
}

// edge e -> (src, dst); e >= E_EDGES are self-loops
static __device__ __forceinline__ void edge_sd(const int* __restrict__ ei, int e, int& s, int& d) {
    if (e < E_EDGES) { s = ei[e]; d = ei[E_EDGES + e]; }
    else             { s = e - E_EDGES; d = s; }
}

// ---------- fp32 -> bf16 convert (row-padded) ----------
__global__ void k_f2b_pad(const float* __restrict__ in, bf16* __restrict__ out,
                          int M, int K, int ldk) {
    int i = blockIdx.x * blockDim.x + threadIdx.x;
    if (i >= M * ldk) return;
    int r = i / ldk, k = i - r * ldk;
    out[i] = __float2bfloat16((k < K) ? in[(size_t)r * K + k] : 0.f);
}

// ---------- fp32 W[K][N] -> bf16 WT[N][ldk] (transposed, K zero-padded) ----------
__global__ void k_f2bt(const float* __restrict__ w, bf16* __restrict__ wt,
                       int K, int N, int ldk) {
    int i = blockIdx.x * blockDim.x + threadIdx.x;
    if (i >= N * ldk) return;
    int n = i / ldk, k = i - n * ldk;
    wt[i] = __float2bfloat16((k < K) ? w[(size_t)k * N + n] : 0.f);
}

// ---------- MFMA bf16 GEMM: C[M,N](ldc) = A[M,K](lda) @ WT[N,K](ldb)^T ----------
// BM=128, BN=128, BK=32; 256 threads = 4 waves. All staging 16B loads/writes.
// 1-D grid, XCD-grouped swizzle (R6: FETCH 774->45MB).
template <typename OutT, int BIAS, int RELU>
__global__ __launch_bounds__(256)
void mfma_mm(const ushort* __restrict__ A, int lda, const ushort* __restrict__ WT, int ldb,
             const float* __restrict__ bias, OutT* __restrict__ C, int ldc,
             int M, int K, int N) {
    const int RT = (M + 127) >> 7;
    const int CT = (N + 127) >> 7;
    const int p = blockIdx.x;
    const int r = (p & 7) + 8 * (p / (8 * CT));
    const int c = (p >> 3) % CT;
    if (r >= RT) return;
    const int m0 = r * 128;
    const int n0 = c * 128;

    __shared__ ushort As[128 * 40];
    __shared__ ushort Bs[128 * 40];
    const int tid = threadIdx.x;
    const int wave = tid >> 6, lane = tid & 63;
    const int quad = lane >> 4, l16 = lane & 15;

    f32x4 acc[2][8];
#pragma unroll
    for (int mi = 0; mi < 2; mi++)
#pragma unroll
        for (int ni = 0; ni < 8; ni++) acc[mi][ni] = (f32x4){0.f, 0.f, 0.f, 0.f};

    const int ar = tid >> 1;
    const int ak = (tid & 1) * 16;

    int grow = m0 + ar; if (grow >= M) grow = M - 1;
    int gn   = n0 + ar; if (gn >= N)   gn = N - 1;
    const ushort* arow = A  + (size_t)grow * lda + ak;
    const ushort* brow = WT + (size_t)gn * ldb + ak;

    for (int kb = 0; kb < K; kb += 32) {
        uint4 a0 = *(const uint4*)(arow + kb);
        uint4 a1 = *(const uint4*)(arow + kb + 8);
        uint4 b0 = *(const uint4*)(brow + kb);
        uint4 b1 = *(const uint4*)(brow + kb + 8);
        *(uint4*)&As[ar * 40 + ak]     = a0;
        *(uint4*)&As[ar * 40 + ak + 8] = a1;
        *(uint4*)&Bs[ar * 40 + ak]     = b0;
        *(uint4*)&Bs[ar * 40 + ak + 8] = b1;
        __syncthreads();
        const int wr = wave * 32;
        short8 af[2], bfr[8];
        af[0] = *(const short8*)&As[(wr + l16) * 40 + quad * 8];
        af[1] = *(const short8*)&As[(wr + 16 + l16) * 40 + quad * 8];
#pragma unroll
        for (int ni = 0; ni < 8; ni++)
            bfr[ni] = *(const short8*)&Bs[(ni * 16 + l16) * 40 + quad * 8];
#pragma unroll
        for (int mi = 0; mi < 2; mi++)
#pragma unroll
            for (int ni = 0; ni < 8; ni++)
                acc[mi][ni] = __builtin_amdgcn_mfma_f32_16x16x32_bf16(
                    af[mi], bfr[ni], acc[mi][ni], 0, 0, 0);
        __syncthreads();
    }
#pragma unroll
    for (int mi = 0; mi < 2; mi++)
#pragma unroll
        for (int ni = 0; ni < 8; ni++)
#pragma unroll
            for (int rg = 0; rg < 4; rg++) {
                int row = m0 + wave * 32 + mi * 16 + quad * 4 + rg;
                int col = n0 + ni * 16 + l16;
                if (row < M && col < N) {
                    float v = acc[mi][ni][rg];
                    if (BIAS) v += bias[col];
                    if (RELU) v = fmaxf(v, 0.f);
                    storev(&C[(size_t)row * ldc + col], v);
                }
            }
}

static inline int mm_grid(int M, int N) {
    int RT = (M + 127) >> 7, CT = (N + 127) >> 7;
    int RTpad = ((RT + 7) >> 3) << 3;
    return RTpad * CT;
}

// ---------- protein fc ----------
__global__ void k_pv(const float* __restrict__ pvec, const float* __restrict__ w,
                     const float* __restrict__ b, float* __restrict__ pv) {
    __shared__ float sm[DP];
    int bg = blockIdx.x, t = threadIdx.x;
    sm[t] = pvec[(size_t)bg * DP + t];
    __syncthreads();
    float acc = 0.f;
    for (int k = 0; k < DP; k++) acc += sm[k] * w[(size_t)k * DP + t];
    pv[(size_t)bg * DP + t] = fmaxf(acc + b[t], 0.f);
}

// ---------- k/v projections ----------
__global__ void k_kv(const float* __restrict__ pv,
                     const float* __restrict__ kw, const float* __restrict__ kb,
                     const float* __restrict__ vw, const float* __restrict__ vb,
                     float* __restrict__ kbuf, float* __restrict__ vbuf) {
    __shared__ float sm[DP];
    int bg = blockIdx.x, t = threadIdx.x;
    sm[t] = pv[(size_t)bg * DP + t];
    __syncthreads();
    int o = t & 127;
    const float* w = (t < 128) ? kw : vw;
    const float* bb = (t < 128) ? kb : vb;
    float acc = 0.f;
    for (int k = 0; k < DP; k++) acc += sm[k] * w[(size_t)k * 128 + o];
    float v = acc + bb[o];
    if (t < 128) kbuf[(size_t)bg * 128 + o] = v;
    else         vbuf[(size_t)bg * 128 + o] = v;
}

// ---------- kq[b,k] = q_w @ k[b]; qbk[b] = q_b . k[b] ----------
__global__ void k_kq(const float* __restrict__ qw, const float* __restrict__ qb,
                     const float* __restrict__ kbuf, float* __restrict__ kq,
                     float* __restrict__ qbk) {
    __shared__ float kb[128];
    int b = blockIdx.x, t = threadIdx.x;  // 128 threads
    kb[t] = kbuf[(size_t)b * 128 + t];
    __syncthreads();
    float acc = 0.f;
    for (int o = 0; o < 128; o++) acc += qw[(size_t)t * 128 + o] * kb[o];
    kq[(size_t)b * 128 + t] = acc;
    if (t == 0) {
        float s = 0.f;
        for (int o = 0; o < 128; o++) s += qb[o] * kb[o];
        qbk[b] = s;
    }
}

// ---------- GAT per-node attention logits (h has ld HF_LD) ----------
__global__ void k_att(const bf16* __restrict__ h, const float* __restrict__ aw_s,
                      const float* __restrict__ aw_d, float* __restrict__ asrc,
                      float* __restrict__ adst) {
    int i = blockIdx.x * blockDim.x + threadIdx.x;
    if (i >= N_NODES * H_HEADS) return;
    int n = i / H_HEADS, hh = i - n * H_HEADS;
    const bf16* hp = h + (size_t)n * HF_LD + hh * FXD;
    const float* ws = aw_s + hh * FXD;
    const float* wd = aw_d + hh * FXD;
    float s1 = 0.f, s2 = 0.f;
    for (int c = 0; c < FXD; c++) { float v = loadv(&hp[c]); s1 += v * ws[c]; s2 += v * wd[c]; }
    asrc[i] = s1; adst[i] = s2;
}

// ---------- edge alpha + segment max over dst ----------
__global__ void k_alpha_max(const int* __restrict__ ei, const float* __restrict__ asrc,
                            const float* __restrict__ adst, float* __restrict__ alpha,
                            unsigned* __restrict__ mseg) {
    int i = blockIdx.x * blockDim.x + threadIdx.x;
    if (i >= ETOT * H_HEADS) return;
    int e = i / H_HEADS, hh = i - e * H_HEADS;
    int s, d; edge_sd(ei, e, s, d);
    float a = asrc[(size_t)s * H_HEADS + hh] + adst[(size_t)d * H_HEADS + hh];
    a = (a >= 0.f) ? a : 0.2f * a;
    alpha[i] = a;
    atomicMax(&mseg[(size_t)d * H_HEADS + hh], f2o(a));
}

// ---------- exp(alpha - m[dst]) in place + segment sum ----------
__global__ void k_exp_sum(const int* __restrict__ ei, float* __restrict__ alpha,
                          const unsigned* __restrict__ mseg, float* __restrict__ sseg) {
    int i = blockIdx.x * blockDim.x + threadIdx.x;
    if (i >= ETOT * H_HEADS) return;
    int e = i / H_HEADS, hh = i - e * H_HEADS;
    int s, d; edge_sd(ei, e, s, d);
    (void)s;
    float ex = expf(alpha[i] - o2f(mseg[(size_t)d * H_HEADS + hh]));
    alpha[i] = ex;
    atomicAdd(&sseg[(size_t)d * H_HEADS + hh], ex);
}

// ---------- CSR build: count, scan, scatter ----------
__global__ void k_count(const int* __restrict__ ei, int* __restrict__ cnt) {
    int e = blockIdx.x * blockDim.x + threadIdx.x;
    if (e >= ETOT) return;
    int d = (e < E_EDGES) ? ei[E_EDGES + e] : e - E_EDGES;
    atomicAdd(&cnt[d], 1);
}

__global__ void k_scan(const int* __restrict__ cnt, int* __restrict__ rowptr,
                       int* __restrict__ cursor) {  // 1 block, 1024 threads
    __shared__ int ps[1024];
    const int t = threadIdx.x;
    const int CH = 40;
    int base = t * CH;
    int s = 0;
    for (int i = 0; i < CH; i++) {
        int idx = base + i;
        if (idx < N_NODES) s += cnt[idx];
    }
    ps[t] = s;
    __syncthreads();
    for (int off = 1; off < 1024; off <<= 1) {
        int v = (t >= off) ? ps[t - off] : 0;
        __syncthreads();
        ps[t] += v;
        __syncthreads();
    }
    int run = (t == 0) ? 0 : ps[t - 1];
    for (int i = 0; i < CH; i++) {
        int idx = base + i;
        if (idx < N_NODES) {
            rowptr[idx] = run;
            cursor[idx] = run;
            run += cnt[idx];
        }
    }
    if (t == 1023) rowptr[N_NODES] = ps[1023];
}

__global__ void k_scatter(const int* __restrict__ ei, int* __restrict__ cursor,
                          int* __restrict__ elist) {
    int e = blockIdx.x * blockDim.x + threadIdx.x;
    if (e >= ETOT) return;
    int d = (e < E_EDGES) ? ei[E_EDGES + e] : e - E_EDGES;
    int pos = atomicAdd(&cursor[d], 1);
    elist[pos] = e;
}

__global__ void k_dinv(const int* __restrict__ cnt, float* __restrict__ dinv) {
    int n = blockIdx.x * blockDim.x + threadIdx.x;
    if (n >= N_NODES) return;
    int c = cnt[n];
    dinv[n] = (c > 0) ? 1.0f / sqrtf((float)c) : 0.f;
}

// ---------- GAT aggregation: wave-per-dst, bf16x8 vector loads ----------
// Lane l owns chunks l and l+64 (8 bf16 each) of the 800-wide padded row.
// Head coefficient per element via __shfl from lanes 0..9 (aval computed
// pre-branch so registers are valid under divergence).
__global__ __launch_bounds__(256)
void k_gat_aggr_v(const int* __restrict__ rowptr, const int* __restrict__ elist,
                  const int* __restrict__ ei, const bf16* __restrict__ h,
                  const float* __restrict__ eexp, const float* __restrict__ sseg,
                  const float* __restrict__ bias, bf16* __restrict__ outb) {
    __shared__ float s_sinv[4][16];
    const int tid = threadIdx.x;
    const int w = tid >> 6, lane = tid & 63;
    const int d = blockIdx.x * 4 + w;
    if (lane < H_HEADS)
        s_sinv[w][lane] = 1.f / (sseg[(size_t)d * H_HEADS + lane] + 1e-16f);
    __syncthreads();
    const int cA = lane * 8;
    const int cB = (lane + 64) * 8;
    const bool hasB = cB < HF_LD;  // lane < 36
    int headA[8], headB[8];
#pragma unroll
    for (int j = 0; j < 8; j++) {
        int ha = (cA + j) / FXD; headA[j] = ha > 9 ? 9 : ha;
        int hb = (cB + j) / FXD; headB[j] = hb > 9 ? 9 : hb;
    }
    float accA[8], accB[8];
#pragma unroll
    for (int j = 0; j < 8; j++) { accA[j] = 0.f; accB[j] = 0.f; }
    const int beg = rowptr[d], end = rowptr[d + 1];
    const ushort* hb16 = (const ushort*)h;
    for (int i = beg; i < end; i++) {
        int e = elist[i];
        int s = (e < E_EDGES) ? ei[e] : e - E_EDGES;
        float aval = 0.f;
        if (lane < H_HEADS)
            aval = eexp[(size_t)e * H_HEADS + lane] * s_sinv[w][lane];
        const ushort* hr = hb16 + (size_t)s * HF_LD;
        short8 va = *(const short8*)(hr + cA);
#pragma unroll
        for (int j = 0; j < 8; j++)
            accA[j] += __shfl(aval, headA[j]) * b2f_bits(va[j]);
        if (hasB) {
            short8 vb = *(const short8*)(hr + cB);
#pragma unroll
            for (int j = 0; j < 8; j++)
                accB[j] += __shfl(aval, headB[j]) * b2f_bits(vb[j]);
        }
    }
    ushort* orow = (ushort*)outb + (size_t)d * HF_LD;
    {
        union { ushort u[8]; uint4 q; } pk;
#pragma unroll
        for (int j = 0; j < 8; j++) {
            float bz = (cA + j < HF) ? bias[cA + j] : 0.f;
            pk.u[j] = f2b_bits(fmaxf(accA[j] + bz, 0.f));
        }
        *(uint4*)(orow + cA) = pk.q;
    }
    if (hasB) {
        union { ushort u[8]; uint4 q; } pk;
#pragma unroll
        for (int j = 0; j < 8; j++) {
            float bz = (cB + j < HF) ? bias[cB + j] : 0.f;
            pk.u[j] = f2b_bits(fmaxf(accB[j] + bz, 0.f));
        }
        *(uint4*)(orow + cB) = pk.q;
    }
}

// ---------- GCN aggregation: wave-per-dst, bf16x8 vector loads ----------
__global__ __launch_bounds__(256)
void k_gcn_aggr_v(const int* __restrict__ rowptr, const int* __restrict__ elist,
                  const int* __restrict__ ei, const bf16* __restrict__ hg,
                  const float* __restrict__ dinv, const float* __restrict__ bias,
                  bf16* __restrict__ outb) {
    const int tid = threadIdx.x;
    const int w = tid >> 6, lane = tid & 63;
    const int d = blockIdx.x * 4 + w;
    const float dv = dinv[d];
    const int cA = lane * 8;
    const int cB = (lane + 64) * 8;
    const bool hasB = cB < HF_LD;
    float accA[8], accB[8];
#pragma unroll
    for (int j = 0; j < 8; j++) { accA[j] = 0.f; accB[j] = 0.f; }
    const int beg = rowptr[d], end = rowptr[d + 1];
    const ushort* hb16 = (const ushort*)hg;
    for (int i = beg; i < end; i++) {
        int e = elist[i];
        int s = (e < E_EDGES) ? ei[e] : e - E_EDGES;
        float wgt = dinv[s] * dv;
        const ushort* hr = hb16 + (size_t)s * HF_LD;
        short8 va = *(const short8*)(hr + cA);
#pragma unroll
        for (int j = 0; j < 8; j++) accA[j] += wgt * b2f_bits(va[j]);
        if (hasB) {
            short8 vb = *(const short8*)(hr + cB);
#pragma unroll
            for (int j = 0; j < 8; j++) accB[j] += wgt * b2f_bits(vb[j]);
        }
    }
    ushort* orow = (ushort*)outb + (size_t)d * HF_LD;
    {
        union { ushort u[8]; uint4 q; } pk;
#pragma unroll
        for (int j = 0; j < 8; j++) {
            float bz = (cA + j < HF) ? bias[cA + j] : 0.f;
            pk.u[j] = f2b_bits(fmaxf(accA[j] + bz, 0.f));
        }
        *(uint4*)(orow + cA) = pk.q;
    }
    if (hasB) {
        union { ushort u[8]; uint4 q; } pk;
#pragma unroll
        for (int j = 0; j < 8; j++) {
            float bz = (cB + j < HF) ? bias[cB + j] : 0.f;
            pk.u[j] = f2b_bits(fmaxf(accB[j] + bz, 0.f));
        }
        *(uint4*)(orow + cB) = pk.q;
    }
}

// ---------- cross-attention scores (one wave per node) ----------
__global__ void k_scores(const float* __restrict__ dn, const float* __restrict__ kq,
                         const float* __restrict__ qbk, const int* __restrict__ batch,
                         float* __restrict__ scores, unsigned* __restrict__ mB) {
    int wv = (blockIdx.x * blockDim.x + threadIdx.x) >> 6;
    int lane = threadIdx.x & 63;
    if (wv >= N_NODES) return;
    int b = batch[wv];
    const float* dp = dn + (size_t)wv * DOUT;
    const float* kp = kq + (size_t)b * DOUT;
    float p = dp[lane] * kp[lane] + dp[lane + 64] * kp[lane + 64];
    for (int off = 32; off > 0; off >>= 1) p += __shfl_down(p, off);
    if (lane == 0) {
        float sc = (p + qbk[b]) * 0.08838834764831845f;  // 1/sqrt(128)
        scores[wv] = sc;
        atomicMax(&mB[b], f2o(sc));
    }
}

__global__ void k_attn_e(const float* __restrict__ scores, const int* __restrict__ batch,
                         const unsigned* __restrict__ mB, float* __restrict__ enode,
                         float* __restrict__ sB) {
    int n = blockIdx.x * blockDim.x + threadIdx.x;
    if (n >= N_NODES) return;
    int b = batch[n];
    float ex = expf(scores[n] - o2f(mB[b]));
    enode[n] = ex;
    atomicAdd(&sB[b], ex);
}

// ---------- attended = dn + attn*v[batch]; segment-max pool ----------
__global__ void k_attend_pool(const float* __restrict__ dn, const float* __restrict__ vbuf,
                              const float* __restrict__ enode, const float* __restrict__ sB,
                              const int* __restrict__ batch, unsigned* __restrict__ pooled) {
    int i = blockIdx.x * blockDim.x + threadIdx.x;
    if (i >= N_NODES * 128) return;
    int n = i >> 7, t = i & 127;
    int b = batch[n];
    float attn = enode[n] / sB[b];
    float val = dn[i] + attn * vbuf[(size_t)b * 128 + t];
    atomicMax(&pooled[(size_t)b * 128 + t], f2o(val));
}

// ---------- decode pool (non-finite -> 0) + concat with pv -> bf16 ----------
__global__ void k_xc(const unsigned* __restrict__ pooled, const float* __restrict__ pv,
                     bf16* __restrict__ xcb) {
    int i = blockIdx.x * blockDim.x + threadIdx.x;
    if (i >= B_GRAPH * 384) return;
    int b = i / 384, t = i - b * 384;
    float v;
    if (t < 128) {
        v = o2f(pooled[(size_t)b * 128 + t]);
        unsigned u = __float_as_uint(v);
        if (((u >> 23) & 0xFF) == 0xFF) v = 0.f;
    } else {
        v = pv[(size_t)b * DP + (t - 128)];
    }
    xcb[i] = __float2bfloat16(v);
}

// ---------- final head ----------
__global__ void k_out(const float* __restrict__ h2, const float* __restrict__ ow,
                      const float* __restrict__ ob, float* __restrict__ out) {
    int row = (blockIdx.x * blockDim.x + threadIdx.x) >> 6;
    int lane = threadIdx.x & 63;
    if (row >= B_GRAPH) return;
    float p = 0.f;
    for (int j = lane; j < 512; j += 64) p += h2[(size_t)row * 512 + j] * ow[j];
    for (int off = 32; off > 0; off >>= 1) p += __shfl_down(p, off);
    if (lane == 0) out[row] = p + ob[0];
}

// ---------- workspace-overflow sentinel ----------
__global__ void k_fail(float* __restrict__ out, int n) {
    int i = blockIdx.x * blockDim.x + threadIdx.x;
    if (i < n) out[i] = 12345.0f;
}

extern "C" void kernel_launch(void* const* d_in, const int* in_sizes, int n_in,
                              void* d_out, int out_size, void* d_ws, size_t ws_size,
                              hipStream_t stream) {
    const float* x        = (const float*)d_in[0];
    const int*   ei       = (const int*)d_in[1];
    const int*   batch    = (const int*)d_in[2];
    const float* pvec     = (const float*)d_in[3];
    const float* pfc_w    = (const float*)d_in[4];
    const float* pfc_b    = (const float*)d_in[5];
    const float* gat_w    = (const float*)d_in[6];
    const float* gat_asrc = (const float*)d_in[7];
    const float* gat_adst = (const float*)d_in[8];
    const float* gat_b    = (const float*)d_in[9];
    const float* gcn_w    = (const float*)d_in[10];
    const float* gcn_b    = (const float*)d_in[11];
    const float* fcg1_w   = (const float*)d_in[12];
    const float* fcg1_b   = (const float*)d_in[13];
    const float* q_w      = (const float*)d_in[14];
    const float* q_b      = (const float*)d_in[15];
    const float* k_w      = (const float*)d_in[16];
    const float* k_b      = (const float*)d_in[17];
    const float* v_w      = (const float*)d_in[18];
    const float* v_b      = (const float*)d_in[19];
    const float* fc1_w    = (const float*)d_in[20];
    const float* fc1_b    = (const float*)d_in[21];
    const float* fc2_w    = (const float*)d_in[22];
    const float* fc2_b    = (const float*)d_in[23];
    const float* out_w    = (const float*)d_in[24];
    const float* out_b    = (const float*)d_in[25];
    float* out = (float*)d_out;

    // ---- workspace layout (bytes, 256-aligned) ----
    char* base = (char*)d_ws;
    size_t off = 0;
    auto alloc = [&](size_t bytes) -> void* {
        void* r = base + off;
        off += (bytes + 255) & ~(size_t)255;
        return r;
    };
    float*    pv      = (float*)alloc((size_t)B_GRAPH * DP * 4);
    bf16*     xb      = (bf16*)alloc((size_t)N_NODES * XK_LD * 2);
    bf16*     wt_gat  = (bf16*)alloc((size_t)HF * XK_LD * 2);
    bf16*     wt_gcn  = (bf16*)alloc((size_t)HF * HF_LD * 2);
    bf16*     wt_fcg1 = (bf16*)alloc((size_t)DOUT * HF_LD * 2);
    bf16*     wt_fc1  = (bf16*)alloc((size_t)1024 * 384 * 2);
    bf16*     wt_fc2  = (bf16*)alloc((size_t)512 * 1024 * 2);
    bf16*     hB      = (bf16*)alloc((size_t)N_NODES * HF_LD * 2);  // h, then hg (ld 800)
    bf16*     g1      = (bf16*)alloc((size_t)N_NODES * HF_LD * 2);  // aggr outs (ld 800)
    float*    asrc    = (float*)alloc((size_t)N_NODES * H_HEADS * 4);
    float*    adst    = (float*)alloc((size_t)N_NODES * H_HEADS * 4);
    unsigned* mseg    = (unsigned*)alloc((size_t)N_NODES * H_HEADS * 4);
    float*    sseg    = (float*)alloc((size_t)N_NODES * H_HEADS * 4);
    float*    alpha   = (float*)alloc((size_t)ETOT * H_HEADS * 4);
    int*      cnt     = (int*)alloc((size_t)N_NODES * 4);
    int*      rowptr  = (int*)alloc((size_t)(N_NODES + 1) * 4);
    int*      cursor  = (int*)alloc((size_t)N_NODES * 4);
    int*      elist   = (int*)alloc((size_t)ETOT * 4);
    float*    dinv    = (float*)alloc((size_t)N_NODES * 4);
    float*    dn      = (float*)alloc((size_t)N_NODES * DOUT * 4);
    float*    kbuf    = (float*)alloc((size_t)B_GRAPH * 128 * 4);
    float*    vbuf    = (float*)alloc((size_t)B_GRAPH * 128 * 4);
    float*    kq      = (float*)alloc((size_t)B_GRAPH * 128 * 4);
    float*    qbk     = (float*)alloc((size_t)B_GRAPH * 4);
    float*    scores  = (float*)alloc((size_t)N_NODES * 4);
    float*    enode   = (float*)alloc((size_t)N_NODES * 4);
    unsigned* mB      = (unsigned*)alloc((size_t)B_GRAPH * 4);
    float*    sB      = (float*)alloc((size_t)B_GRAPH * 4);
    unsigned* pooled  = (unsigned*)alloc((size_t)B_GRAPH * 128 * 4);
    bf16*     xcb     = (bf16*)alloc((size_t)B_GRAPH * 384 * 2);
    bf16*     h1b     = (bf16*)alloc((size_t)B_GRAPH * 1024 * 2);
    float*    h2      = (float*)alloc((size_t)B_GRAPH * 512 * 4);

    if (off > ws_size) {
        k_fail<<<(out_size + 255) / 256, 256, 0, stream>>>(out, out_size);
        return;
    }

    // ---- zero accumulators ----
    (void)hipMemsetAsync(mseg, 0, (size_t)N_NODES * H_HEADS * 4, stream);
    (void)hipMemsetAsync(sseg, 0, (size_t)N_NODES * H_HEADS * 4, stream);
    (void)hipMemsetAsync(cnt, 0, (size_t)N_NODES * 4, stream);
    (void)hipMemsetAsync(mB, 0, (size_t)B_GRAPH * 4, stream);
    (void)hipMemsetAsync(sB, 0, (size_t)B_GRAPH * 4, stream);
    (void)hipMemsetAsync(pooled, 0, (size_t)B_GRAPH * 128 * 4, stream);

    // ---- bf16 conversions / weight transposes ----
    k_f2b_pad<<<(N_NODES * XK_LD + 255) / 256, 256, 0, stream>>>(x, xb, N_NODES, FXD, XK_LD);
    k_f2bt<<<(HF * XK_LD + 255) / 256, 256, 0, stream>>>(gat_w, wt_gat, FXD, HF, XK_LD);
    k_f2bt<<<(HF * HF_LD + 255) / 256, 256, 0, stream>>>(gcn_w, wt_gcn, HF, HF, HF_LD);
    k_f2bt<<<(DOUT * HF_LD + 255) / 256, 256, 0, stream>>>(fcg1_w, wt_fcg1, HF, DOUT, HF_LD);
    k_f2bt<<<(1024 * 384 + 255) / 256, 256, 0, stream>>>(fc1_w, wt_fc1, 384, 1024, 384);
    k_f2bt<<<(512 * 1024 + 255) / 256, 256, 0, stream>>>(fc2_w, wt_fc2, 1024, 512, 1024);

    // ---- protein path ----
    k_pv<<<B_GRAPH, 256, 0, stream>>>(pvec, pfc_w, pfc_b, pv);
    k_kv<<<B_GRAPH, 256, 0, stream>>>(pv, k_w, k_b, v_w, v_b, kbuf, vbuf);
    k_kq<<<B_GRAPH, 128, 0, stream>>>(q_w, q_b, kbuf, kq, qbk);

    // ---- CSR build ----
    k_count<<<(ETOT + 255) / 256, 256, 0, stream>>>(ei, cnt);
    k_scan<<<1, 1024, 0, stream>>>(cnt, rowptr, cursor);
    k_scatter<<<(ETOT + 255) / 256, 256, 0, stream>>>(ei, cursor, elist);
    k_dinv<<<(N_NODES + 255) / 256, 256, 0, stream>>>(cnt, dinv);

    // ---- GAT ----
    mfma_mm<bf16, 0, 0><<<mm_grid(N_NODES, HF), 256, 0, stream>>>(
        (const ushort*)xb, XK_LD, (const ushort*)wt_gat, XK_LD, nullptr, hB, HF_LD,
        N_NODES, XK_LD, HF);
    k_att<<<(N_NODES * H_HEADS + 255) / 256, 256, 0, stream>>>(hB, gat_asrc, gat_adst,
                                                               asrc, adst);
    k_alpha_max<<<(ETOT * H_HEADS + 255) / 256, 256, 0, stream>>>(ei, asrc, adst, alpha, mseg);
    k_exp_sum<<<(ETOT * H_HEADS + 255) / 256, 256, 0, stream>>>(ei, alpha, mseg, sseg);
    k_gat_aggr_v<<<N_NODES / 4, 256, 0, stream>>>(rowptr, elist, ei, hB, alpha, sseg,
                                                  gat_b, g1);

    // ---- GCN ----
    mfma_mm<bf16, 0, 0><<<mm_grid(N_NODES, HF), 256, 0, stream>>>(
        (const ushort*)g1, HF_LD, (const ushort*)wt_gcn, HF_LD, nullptr, hB, HF_LD,
        N_NODES, HF_LD, HF);
    k_gcn_aggr_v<<<N_NODES / 4, 256, 0, stream>>>(rowptr, elist, ei, hB, dinv, gcn_b, g1);

    // ---- fc_g1 (bf16 MFMA, fp32 out, bias+relu) ----
    mfma_mm<float, 1, 1><<<mm_grid(N_NODES, DOUT), 256, 0, stream>>>(
        (const ushort*)g1, HF_LD, (const ushort*)wt_fcg1, HF_LD, fcg1_b, dn, DOUT,
        N_NODES, HF_LD, DOUT);

    // ---- cross attention + pool ----
    k_scores<<<(N_NODES * 64 + 255) / 256, 256, 0, stream>>>(dn, kq, qbk, batch, scores, mB);
    k_attn_e<<<(N_NODES + 255) / 256, 256, 0, stream>>>(scores, batch, mB, enode, sB);
    k_attend_pool<<<(N_NODES * 128 + 255) / 256, 256, 0, stream>>>(dn, vbuf, enode,
                                                                   sB, batch, pooled);
    k_xc<<<(B_GRAPH * 384 + 255) / 256, 256, 0, stream>>>(pooled, pv, xcb);

    // ---- head MLP (bf16 MFMA) ----
    mfma_mm<bf16, 1, 1><<<mm_grid(B_GRAPH, 1024), 256, 0, stream>>>(
        (const ushort*)xcb, 384, (const ushort*)wt_fc1, 384, fc1_b, h1b, 1024,
        B_GRAPH, 384, 1024);
    mfma_mm<float, 1, 1><<<mm_grid(B_GRAPH, 512), 256, 0, stream>>>(
        (const ushort*)h1b, 1024, (const ushort*)wt_fc2, 1024, fc2_b, h2, 512,
        B_GRAPH, 1024, 512);
    k_out<<<(B_GRAPH * 64 + 255) / 256, 256, 0, stream>>>(h2, out_w, out_b, out);
}

// Round 9
// 703.708 us; speedup vs baseline: 1.5768x; 1.1355x over previous
//
#include <hip/hip_runtime.h>
#include <hip/hip_bf16.h>
#include <math.h>

#define N_NODES 40000
#define E_EDGES 160000
#define ETOT    (E_EDGES + N_NODES)   // 200000 (with self-loops)
#define B_GRAPH 1024
#define FXD     78
#define H_HEADS 10
#define HF      (H_HEADS * FXD)       // 780
#define HF_LD   800                   // padded leading dim (16B-aligned rows)
#define XK_LD   96                    // padded K for x (78 -> 96)
#define DOUT    128
#define DP      256
#define SCAN_TILES 40                 // 40 x 1024 >= 40000

typedef __hip_bfloat16 bf16;
typedef __attribute__((ext_vector_type(8))) short short8;
typedef __attribute__((ext_vector_type(4))) float f32x4;

// ---------- ordered-float encoding for atomic max on unsigned ----------
static __device__ __forceinline__ unsigned f2o(float f) {
    unsigned u = __float_as_uint(f);
    return (u & 0x80000000u) ? ~u : (u | 0x80000000u);
}
static __device__ __forceinline__ float o2f(unsigned o) {
    unsigned u = (o & 0x80000000u) ? (o & 0x7FFFFFFFu) : ~o;
    return __uint_as_float(u);
}

static __device__ __forceinline__ void storev(float* p, float v) { *p = v; }
static __device__ __forceinline__ void storev(bf16* p, float v) { *p = __float2bfloat16(v); }
static __device__ __forceinline__ float loadv(const float* p) { return *p; }
static __device__ __forceinline__ float loadv(const bf16* p) { return __bfloat162float(*p); }

static __device__ __forceinline__ ushort f2b_bits(float v) {
    bf16 b = __float2bfloat16(v);
    return *reinterpret_cast<ushort*>(&b);
}
static __device__ __forceinline__ float b2f_bits(short u) {
    return __uint_as_float(((unsigned)(unsigned short)u) << 16);
}

// edge e -> (src, dst); e >= E_EDGES are self-loops
static __device__ __forceinline__ void edge_sd(const int* __restrict__ ei, int e, int& s, int& d) {
    if (e < E_EDGES) { s = ei[e]; d = ei[E_EDGES + e]; }
    else             { s = e - E_EDGES; d = s; }
}

// ---------- fp32 -> bf16 convert (row-padded) ----------
__global__ void k_f2b_pad(const float* __restrict__ in, bf16* __restrict__ out,
                          int M, int K, int ldk) {
    int i = blockIdx.x * blockDim.x + threadIdx.x;
    if (i >= M * ldk) return;
    int r = i / ldk, k = i - r * ldk;
    out[i] = __float2bfloat16((k < K) ? in[(size_t)r * K + k] : 0.f);
}

// ---------- fp32 W[K][N] -> bf16 WT[N][ldk] (transposed, K zero-padded) ----------
__global__ void k_f2bt(const float* __restrict__ w, bf16* __restrict__ wt,
                       int K, int N, int ldk) {
    int i = blockIdx.x * blockDim.x + threadIdx.x;
    if (i >= N * ldk) return;
    int n = i / ldk, k = i - n * ldk;
    wt[i] = __float2bfloat16((k < K) ? w[(size_t)k * N + n] : 0.f);
}

// ---------- MFMA bf16 GEMM: C[M,N](ldc) = A[M,K](lda) @ WT[N,K](ldb)^T ----------
template <typename OutT, int BIAS, int RELU>
__global__ __launch_bounds__(256)
void mfma_mm(const ushort* __restrict__ A, int lda, const ushort* __restrict__ WT, int ldb,
             const float* __restrict__ bias, OutT* __restrict__ C, int ldc,
             int M, int K, int N) {
    const int RT = (M + 127) >> 7;
    const int CT = (N + 127) >> 7;
    const int p = blockIdx.x;
    const int r = (p & 7) + 8 * (p / (8 * CT));
    const int c = (p >> 3) % CT;
    if (r >= RT) return;
    const int m0 = r * 128;
    const int n0 = c * 128;

    __shared__ ushort As[128 * 40];
    __shared__ ushort Bs[128 * 40];
    const int tid = threadIdx.x;
    const int wave = tid >> 6, lane = tid & 63;
    const int quad = lane >> 4, l16 = lane & 15;

    f32x4 acc[2][8];
#pragma unroll
    for (int mi = 0; mi < 2; mi++)
#pragma unroll
        for (int ni = 0; ni < 8; ni++) acc[mi][ni] = (f32x4){0.f, 0.f, 0.f, 0.f};

    const int ar = tid >> 1;
    const int ak = (tid & 1) * 16;

    int grow = m0 + ar; if (grow >= M) grow = M - 1;
    int gn   = n0 + ar; if (gn >= N)   gn = N - 1;
    const ushort* arow = A  + (size_t)grow * lda + ak;
    const ushort* brow = WT + (size_t)gn * ldb + ak;

    for (int kb = 0; kb < K; kb += 32) {
        uint4 a0 = *(const uint4*)(arow + kb);
        uint4 a1 = *(const uint4*)(arow + kb + 8);
        uint4 b0 = *(const uint4*)(brow + kb);
        uint4 b1 = *(const uint4*)(brow + kb + 8);
        *(uint4*)&As[ar * 40 + ak]     = a0;
        *(uint4*)&As[ar * 40 + ak + 8] = a1;
        *(uint4*)&Bs[ar * 40 + ak]     = b0;
        *(uint4*)&Bs[ar * 40 + ak + 8] = b1;
        __syncthreads();
        const int wr = wave * 32;
        short8 af[2], bfr[8];
        af[0] = *(const short8*)&As[(wr + l16) * 40 + quad * 8];
        af[1] = *(const short8*)&As[(wr + 16 + l16) * 40 + quad * 8];
#pragma unroll
        for (int ni = 0; ni < 8; ni++)
            bfr[ni] = *(const short8*)&Bs[(ni * 16 + l16) * 40 + quad * 8];
#pragma unroll
        for (int mi = 0; mi < 2; mi++)
#pragma unroll
            for (int ni = 0; ni < 8; ni++)
                acc[mi][ni] = __builtin_amdgcn_mfma_f32_16x16x32_bf16(
                    af[mi], bfr[ni], acc[mi][ni], 0, 0, 0);
        __syncthreads();
    }
#pragma unroll
    for (int mi = 0; mi < 2; mi++)
#pragma unroll
        for (int ni = 0; ni < 8; ni++)
#pragma unroll
            for (int rg = 0; rg < 4; rg++) {
                int row = m0 + wave * 32 + mi * 16 + quad * 4 + rg;
                int col = n0 + ni * 16 + l16;
                if (row < M && col < N) {
                    float v = acc[mi][ni][rg];
                    if (BIAS) v += bias[col];
                    if (RELU) v = fmaxf(v, 0.f);
                    storev(&C[(size_t)row * ldc + col], v);
                }
            }
}

static inline int mm_grid(int M, int N) {
    int RT = (M + 127) >> 7, CT = (N + 127) >> 7;
    int RTpad = ((RT + 7) >> 3) << 3;
    return RTpad * CT;
}

// ---------- protein fc ----------
__global__ void k_pv(const float* __restrict__ pvec, const float* __restrict__ w,
                     const float* __restrict__ b, float* __restrict__ pv) {
    __shared__ float sm[DP];
    int bg = blockIdx.x, t = threadIdx.x;
    sm[t] = pvec[(size_t)bg * DP + t];
    __syncthreads();
    float acc = 0.f;
    for (int k = 0; k < DP; k++) acc += sm[k] * w[(size_t)k * DP + t];
    pv[(size_t)bg * DP + t] = fmaxf(acc + b[t], 0.f);
}

// ---------- k/v projections ----------
__global__ void k_kv(const float* __restrict__ pv,
                     const float* __restrict__ kw, const float* __restrict__ kb,
                     const float* __restrict__ vw, const float* __restrict__ vb,
                     float* __restrict__ kbuf, float* __restrict__ vbuf) {
    __shared__ float sm[DP];
    int bg = blockIdx.x, t = threadIdx.x;
    sm[t] = pv[(size_t)bg * DP + t];
    __syncthreads();
    int o = t & 127;
    const float* w = (t < 128) ? kw : vw;
    const float* bb = (t < 128) ? kb : vb;
    float acc = 0.f;
    for (int k = 0; k < DP; k++) acc += sm[k] * w[(size_t)k * 128 + o];
    float v = acc + bb[o];
    if (t < 128) kbuf[(size_t)bg * 128 + o] = v;
    else         vbuf[(size_t)bg * 128 + o] = v;
}

// ---------- kq[b,k] = q_w @ k[b]; qbk[b] = q_b . k[b] ----------
__global__ void k_kq(const float* __restrict__ qw, const float* __restrict__ qb,
                     const float* __restrict__ kbuf, float* __restrict__ kq,
                     float* __restrict__ qbk) {
    __shared__ float kb[128];
    int b = blockIdx.x, t = threadIdx.x;  // 128 threads
    kb[t] = kbuf[(size_t)b * 128 + t];
    __syncthreads();
    float acc = 0.f;
    for (int o = 0; o < 128; o++) acc += qw[(size_t)t * 128 + o] * kb[o];
    kq[(size_t)b * 128 + t] = acc;
    if (t == 0) {
        float s = 0.f;
        for (int o = 0; o < 128; o++) s += qb[o] * kb[o];
        qbk[b] = s;
    }
}

// ---------- GAT per-node attention logits (h has ld HF_LD, bf16x2 loads) ----------
__global__ void k_att(const bf16* __restrict__ h, const float* __restrict__ aw_s,
                      const float* __restrict__ aw_d, float* __restrict__ asrc,
                      float* __restrict__ adst) {
    int i = blockIdx.x * blockDim.x + threadIdx.x;
    if (i >= N_NODES * H_HEADS) return;
    int n = i / H_HEADS, hh = i - n * H_HEADS;
    const ushort* hp = (const ushort*)h + (size_t)n * HF_LD + hh * FXD;  // even offset
    const float* ws = aw_s + hh * FXD;
    const float* wd = aw_d + hh * FXD;
    float s1 = 0.f, s2 = 0.f;
    for (int c = 0; c < FXD; c += 2) {
        uint dd = *(const uint*)(hp + c);
        float v0 = b2f_bits((ushort)dd), v1 = b2f_bits((ushort)(dd >> 16));
        s1 += v0 * ws[c] + v1 * ws[c + 1];
        s2 += v0 * wd[c] + v1 * wd[c + 1];
    }
    asrc[i] = s1; adst[i] = s2;
}

// ---------- edge alpha + segment max over dst ----------
__global__ void k_alpha_max(const int* __restrict__ ei, const float* __restrict__ asrc,
                            const float* __restrict__ adst, float* __restrict__ alpha,
                            unsigned* __restrict__ mseg) {
    int i = blockIdx.x * blockDim.x + threadIdx.x;
    if (i >= ETOT * H_HEADS) return;
    int e = i / H_HEADS, hh = i - e * H_HEADS;
    int s, d; edge_sd(ei, e, s, d);
    float a = asrc[(size_t)s * H_HEADS + hh] + adst[(size_t)d * H_HEADS + hh];
    a = (a >= 0.f) ? a : 0.2f * a;
    alpha[i] = a;
    atomicMax(&mseg[(size_t)d * H_HEADS + hh], f2o(a));
}

// ---------- exp(alpha - m[dst]) in place + segment sum ----------
__global__ void k_exp_sum(const int* __restrict__ ei, float* __restrict__ alpha,
                          const unsigned* __restrict__ mseg, float* __restrict__ sseg) {
    int i = blockIdx.x * blockDim.x + threadIdx.x;
    if (i >= ETOT * H_HEADS) return;
    int e = i / H_HEADS, hh = i - e * H_HEADS;
    int s, d; edge_sd(ei, e, s, d);
    (void)s;
    float ex = expf(alpha[i] - o2f(mseg[(size_t)d * H_HEADS + hh]));
    alpha[i] = ex;
    atomicAdd(&sseg[(size_t)d * H_HEADS + hh], ex);
}

// ---------- CSR build: count, hierarchical scan, scatter ----------
__global__ void k_count(const int* __restrict__ ei, int* __restrict__ cnt) {
    int e = blockIdx.x * blockDim.x + threadIdx.x;
    if (e >= ETOT) return;
    int d = (e < E_EDGES) ? ei[E_EDGES + e] : e - E_EDGES;
    atomicAdd(&cnt[d], 1);
}

// pass 1: per-tile totals (tile = 1024 elems, 256 threads x int4)
__global__ void k_scan_tile(const int* __restrict__ cnt, int* __restrict__ tile_sums) {
    __shared__ int sm[256];
    int b = blockIdx.x, t = threadIdx.x;
    int idx = b * 1024 + t * 4;
    int4 v = {0, 0, 0, 0};
    if (idx + 3 < N_NODES) v = *(const int4*)(cnt + idx);
    else {
        v.x = (idx     < N_NODES) ? cnt[idx]     : 0;
        v.y = (idx + 1 < N_NODES) ? cnt[idx + 1] : 0;
        v.z = (idx + 2 < N_NODES) ? cnt[idx + 2] : 0;
        v.w = (idx + 3 < N_NODES) ? cnt[idx + 3] : 0;
    }
    sm[t] = v.x + v.y + v.z + v.w;
    __syncthreads();
    for (int off = 128; off > 0; off >>= 1) {
        if (t < off) sm[t] += sm[t + off];
        __syncthreads();
    }
    if (t == 0) tile_sums[b] = sm[0];
}

// pass 2: exclusive scan of tile sums (tiny) + total -> rowptr[N]
__global__ void k_scan_top(const int* __restrict__ tile_sums, int* __restrict__ tile_off,
                           int* __restrict__ rowptr) {
    if (threadIdx.x == 0) {
        int run = 0;
        for (int i = 0; i < SCAN_TILES; i++) { tile_off[i] = run; run += tile_sums[i]; }
        rowptr[N_NODES] = run;
    }
}

// pass 3: per-tile exclusive scan + tile offset -> rowptr, cursor
__global__ void k_scan_write(const int* __restrict__ cnt, const int* __restrict__ tile_off,
                             int* __restrict__ rowptr, int* __restrict__ cursor) {
    __shared__ int sm[256];
    int b = blockIdx.x, t = threadIdx.x;
    int idx = b * 1024 + t * 4;
    int4 v = {0, 0, 0, 0};
    if (idx + 3 < N_NODES) v = *(const int4*)(cnt + idx);
    else {
        v.x = (idx     < N_NODES) ? cnt[idx]     : 0;
        v.y = (idx + 1 < N_NODES) ? cnt[idx + 1] : 0;
        v.z = (idx + 2 < N_NODES) ? cnt[idx + 2] : 0;
        v.w = (idx + 3 < N_NODES) ? cnt[idx + 3] : 0;
    }
    int tsum = v.x + v.y + v.z + v.w;
    sm[t] = tsum;
    __syncthreads();
    for (int off = 1; off < 256; off <<= 1) {
        int add = (t >= off) ? sm[t - off] : 0;
        __syncthreads();
        sm[t] += add;
        __syncthreads();
    }
    int toff = tile_off[b] + sm[t] - tsum;  // exclusive thread offset
    int e0 = toff, e1 = e0 + v.x, e2 = e1 + v.y, e3 = e2 + v.z;
    if (idx     < N_NODES) { rowptr[idx]     = e0; cursor[idx]     = e0; }
    if (idx + 1 < N_NODES) { rowptr[idx + 1] = e1; cursor[idx + 1] = e1; }
    if (idx + 2 < N_NODES) { rowptr[idx + 2] = e2; cursor[idx + 2] = e2; }
    if (idx + 3 < N_NODES) { rowptr[idx + 3] = e3; cursor[idx + 3] = e3; }
}

__global__ void k_scatter(const int* __restrict__ ei, int* __restrict__ cursor,
                          int* __restrict__ elist) {
    int e = blockIdx.x * blockDim.x + threadIdx.x;
    if (e >= ETOT) return;
    int d = (e < E_EDGES) ? ei[E_EDGES + e] : e - E_EDGES;
    int pos = atomicAdd(&cursor[d], 1);
    elist[pos] = e;
}

__global__ void k_dinv(const int* __restrict__ cnt, float* __restrict__ dinv) {
    int n = blockIdx.x * blockDim.x + threadIdx.x;
    if (n >= N_NODES) return;
    int c = cnt[n];
    dinv[n] = (c > 0) ? 1.0f / sqrtf((float)c) : 0.f;
}

// ---------- GAT aggregation: wave-per-dst, bf16x8 vector loads ----------
__global__ __launch_bounds__(256)
void k_gat_aggr_v(const int* __restrict__ rowptr, const int* __restrict__ elist,
                  const int* __restrict__ ei, const bf16* __restrict__ h,
                  const float* __restrict__ eexp, const float* __restrict__ sseg,
                  const float* __restrict__ bias, bf16* __restrict__ outb) {
    __shared__ float s_sinv[4][16];
    const int tid = threadIdx.x;
    const int w = tid >> 6, lane = tid & 63;
    const int d = blockIdx.x * 4 + w;
    if (lane < H_HEADS)
        s_sinv[w][lane] = 1.f / (sseg[(size_t)d * H_HEADS + lane] + 1e-16f);
    __syncthreads();
    const int cA = lane * 8;
    const int cB = (lane + 64) * 8;
    const bool hasB = cB < HF_LD;  // lane < 36
    int headA[8], headB[8];
#pragma unroll
    for (int j = 0; j < 8; j++) {
        int ha = (cA + j) / FXD; headA[j] = ha > 9 ? 9 : ha;
        int hb = (cB + j) / FXD; headB[j] = hb > 9 ? 9 : hb;
    }
    float accA[8], accB[8];
#pragma unroll
    for (int j = 0; j < 8; j++) { accA[j] = 0.f; accB[j] = 0.f; }
    const int beg = rowptr[d], end = rowptr[d + 1];
    const ushort* hb16 = (const ushort*)h;
    for (int i = beg; i < end; i++) {
        int e = elist[i];
        int s = (e < E_EDGES) ? ei[e] : e - E_EDGES;
        float aval = 0.f;
        if (lane < H_HEADS)
            aval = eexp[(size_t)e * H_HEADS + lane] * s_sinv[w][lane];
        const ushort* hr = hb16 + (size_t)s * HF_LD;
        short8 va = *(const short8*)(hr + cA);
#pragma unroll
        for (int j = 0; j < 8; j++)
            accA[j] += __shfl(aval, headA[j]) * b2f_bits(va[j]);
        if (hasB) {
            short8 vb = *(const short8*)(hr + cB);
#pragma unroll
            for (int j = 0; j < 8; j++)
                accB[j] += __shfl(aval, headB[j]) * b2f_bits(vb[j]);
        }
    }
    ushort* orow = (ushort*)outb + (size_t)d * HF_LD;
    {
        union { ushort u[8]; uint4 q; } pk;
#pragma unroll
        for (int j = 0; j < 8; j++) {
            float bz = (cA + j < HF) ? bias[cA + j] : 0.f;
            pk.u[j] = f2b_bits(fmaxf(accA[j] + bz, 0.f));
        }
        *(uint4*)(orow + cA) = pk.q;
    }
    if (hasB) {
        union { ushort u[8]; uint4 q; } pk;
#pragma unroll
        for (int j = 0; j < 8; j++) {
            float bz = (cB + j < HF) ? bias[cB + j] : 0.f;
            pk.u[j] = f2b_bits(fmaxf(accB[j] + bz, 0.f));
        }
        *(uint4*)(orow + cB) = pk.q;
    }
}

// ---------- GCN aggregation: wave-per-dst, bf16x8 vector loads ----------
__global__ __launch_bounds__(256)
void k_gcn_aggr_v(const int* __restrict__ rowptr, const int* __restrict__ elist,
                  const int* __restrict__ ei, const bf16* __restrict__ hg,
                  const float* __restrict__ dinv, const float* __restrict__ bias,
                  bf16* __restrict__ outb) {
    const int tid = threadIdx.x;
    const int w = tid >> 6, lane = tid & 63;
    const int d = blockIdx.x * 4 + w;
    const float dv = dinv[d];
    const int cA = lane * 8;
    const int cB = (lane + 64) * 8;
    const bool hasB = cB < HF_LD;
    float accA[8], accB[8];
#pragma unroll
    for (int j = 0; j < 8; j++) { accA[j] = 0.f; accB[j] = 0.f; }
    const int beg = rowptr[d], end = rowptr[d + 1];
    const ushort* hb16 = (const ushort*)hg;
    for (int i = beg; i < end; i++) {
        int e = elist[i];
        int s = (e < E_EDGES) ? ei[e] : e - E_EDGES;
        float wgt = dinv[s] * dv;
        const ushort* hr = hb16 + (size_t)s * HF_LD;
        short8 va = *(const short8*)(hr + cA);
#pragma unroll
        for (int j = 0; j < 8; j++) accA[j] += wgt * b2f_bits(va[j]);
        if (hasB) {
            short8 vb = *(const short8*)(hr + cB);
#pragma unroll
            for (int j = 0; j < 8; j++) accB[j] += wgt * b2f_bits(vb[j]);
        }
    }
    ushort* orow = (ushort*)outb + (size_t)d * HF_LD;
    {
        union { ushort u[8]; uint4 q; } pk;
#pragma unroll
        for (int j = 0; j < 8; j++) {
            float bz = (cA + j < HF) ? bias[cA + j] : 0.f;
            pk.u[j] = f2b_bits(fmaxf(accA[j] + bz, 0.f));
        }
        *(uint4*)(orow + cA) = pk.q;
    }
    if (hasB) {
        union { ushort u[8]; uint4 q; } pk;
#pragma unroll
        for (int j = 0; j < 8; j++) {
            float bz = (cB + j < HF) ? bias[cB + j] : 0.f;
            pk.u[j] = f2b_bits(fmaxf(accB[j] + bz, 0.f));
        }
        *(uint4*)(orow + cB) = pk.q;
    }
}

// ---------- cross-attention scores (one wave per node) ----------
__global__ void k_scores(const float* __restrict__ dn, const float* __restrict__ kq,
                         const float* __restrict__ qbk, const int* __restrict__ batch,
                         float* __restrict__ scores, unsigned* __restrict__ mB) {
    int wv = (blockIdx.x * blockDim.x + threadIdx.x) >> 6;
    int lane = threadIdx.x & 63;
    if (wv >= N_NODES) return;
    int b = batch[wv];
    const float* dp = dn + (size_t)wv * DOUT;
    const float* kp = kq + (size_t)b * DOUT;
    float p = dp[lane] * kp[lane] + dp[lane + 64] * kp[lane + 64];
    for (int off = 32; off > 0; off >>= 1) p += __shfl_down(p, off);
    if (lane == 0) {
        float sc = (p + qbk[b]) * 0.08838834764831845f;  // 1/sqrt(128)
        scores[wv] = sc;
        atomicMax(&mB[b], f2o(sc));
    }
}

__global__ void k_attn_e(const float* __restrict__ scores, const int* __restrict__ batch,
                         const unsigned* __restrict__ mB, float* __restrict__ enode,
                         float* __restrict__ sB) {
    int n = blockIdx.x * blockDim.x + threadIdx.x;
    if (n >= N_NODES) return;
    int b = batch[n];
    float ex = expf(scores[n] - o2f(mB[b]));
    enode[n] = ex;
    atomicAdd(&sB[b], ex);
}

// ---------- attended = dn + attn*v[batch]; segment-max pool ----------
__global__ void k_attend_pool(const float* __restrict__ dn, const float* __restrict__ vbuf,
                              const float* __restrict__ enode, const float* __restrict__ sB,
                              const int* __restrict__ batch, unsigned* __restrict__ pooled) {
    int i = blockIdx.x * blockDim.x + threadIdx.x;
    if (i >= N_NODES * 128) return;
    int n = i >> 7, t = i & 127;
    int b = batch[n];
    float attn = enode[n] / sB[b];
    float val = dn[i] + attn * vbuf[(size_t)b * 128 + t];
    atomicMax(&pooled[(size_t)b * 128 + t], f2o(val));
}

// ---------- decode pool (non-finite -> 0) + concat with pv -> bf16 ----------
__global__ void k_xc(const unsigned* __restrict__ pooled, const float* __restrict__ pv,
                     bf16* __restrict__ xcb) {
    int i = blockIdx.x * blockDim.x + threadIdx.x;
    if (i >= B_GRAPH * 384) return;
    int b = i / 384, t = i - b * 384;
    float v;
    if (t < 128) {
        v = o2f(pooled[(size_t)b * 128 + t]);
        unsigned u = __float_as_uint(v);
        if (((u >> 23) & 0xFF) == 0xFF) v = 0.f;
    } else {
        v = pv[(size_t)b * DP + (t - 128)];
    }
    xcb[i] = __float2bfloat16(v);
}

// ---------- final head ----------
__global__ void k_out(const float* __restrict__ h2, const float* __restrict__ ow,
                      const float* __restrict__ ob, float* __restrict__ out) {
    int row = (blockIdx.x * blockDim.x + threadIdx.x) >> 6;
    int lane = threadIdx.x & 63;
    if (row >= B_GRAPH) return;
    float p = 0.f;
    for (int j = lane; j < 512; j += 64) p += h2[(size_t)row * 512 + j] * ow[j];
    for (int off = 32; off > 0; off >>= 1) p += __shfl_down(p, off);
    if (lane == 0) out[row] = p + ob[0];
}

// ---------- workspace-overflow sentinel ----------
__global__ void k_fail(float* __restrict__ out, int n) {
    int i = blockIdx.x * blockDim.x + threadIdx.x;
    if (i < n) out[i] = 12345.0f;
}

extern "C" void kernel_launch(void* const* d_in, const int* in_sizes, int n_in,
                              void* d_out, int out_size, void* d_ws, size_t ws_size,
                              hipStream_t stream) {
    const float* x        = (const float*)d_in[0];
    const int*   ei       = (const int*)d_in[1];
    const int*   batch    = (const int*)d_in[2];
    const float* pvec     = (const float*)d_in[3];
    const float* pfc_w    = (const float*)d_in[4];
    const float* pfc_b    = (const float*)d_in[5];
    const float* gat_w    = (const float*)d_in[6];
    const float* gat_asrc = (const float*)d_in[7];
    const float* gat_adst = (const float*)d_in[8];
    const float* gat_b    = (const float*)d_in[9];
    const float* gcn_w    = (const float*)d_in[10];
    const float* gcn_b    = (const float*)d_in[11];
    const float* fcg1_w   = (const float*)d_in[12];
    const float* fcg1_b   = (const float*)d_in[13];
    const float* q_w      = (const float*)d_in[14];
    const float* q_b      = (const float*)d_in[15];
    const float* k_w      = (const float*)d_in[16];
    const float* k_b      = (const float*)d_in[17];
    const float* v_w      = (const float*)d_in[18];
    const float* v_b      = (const float*)d_in[19];
    const float* fc1_w    = (const float*)d_in[20];
    const float* fc1_b    = (const float*)d_in[21];
    const float* fc2_w    = (const float*)d_in[22];
    const float* fc2_b    = (const float*)d_in[23];
    const float* out_w    = (const float*)d_in[24];
    const float* out_b    = (const float*)d_in[25];
    float* out = (float*)d_out;

    // ---- workspace layout (bytes, 256-aligned) ----
    char* base = (char*)d_ws;
    size_t off = 0;
    auto alloc = [&](size_t bytes) -> void* {
        void* r = base + off;
        off += (bytes + 255) & ~(size_t)255;
        return r;
    };
    float*    pv      = (float*)alloc((size_t)B_GRAPH * DP * 4);
    bf16*     xb      = (bf16*)alloc((size_t)N_NODES * XK_LD * 2);
    bf16*     wt_gat  = (bf16*)alloc((size_t)HF * XK_LD * 2);
    bf16*     wt_gcn  = (bf16*)alloc((size_t)HF * HF_LD * 2);
    bf16*     wt_fcg1 = (bf16*)alloc((size_t)DOUT * HF_LD * 2);
    bf16*     wt_fc1  = (bf16*)alloc((size_t)1024 * 384 * 2);
    bf16*     wt_fc2  = (bf16*)alloc((size_t)512 * 1024 * 2);
    bf16*     hB      = (bf16*)alloc((size_t)N_NODES * HF_LD * 2);  // h, then hg (ld 800)
    bf16*     g1      = (bf16*)alloc((size_t)N_NODES * HF_LD * 2);  // aggr outs (ld 800)
    float*    asrc    = (float*)alloc((size_t)N_NODES * H_HEADS * 4);
    float*    adst    = (float*)alloc((size_t)N_NODES * H_HEADS * 4);
    unsigned* mseg    = (unsigned*)alloc((size_t)N_NODES * H_HEADS * 4);
    float*    sseg    = (float*)alloc((size_t)N_NODES * H_HEADS * 4);
    float*    alpha   = (float*)alloc((size_t)ETOT * H_HEADS * 4);
    int*      cnt     = (int*)alloc((size_t)N_NODES * 4);
    int*      rowptr  = (int*)alloc((size_t)(N_NODES + 1) * 4);
    int*      cursor  = (int*)alloc((size_t)N_NODES * 4);
    int*      elist   = (int*)alloc((size_t)ETOT * 4);
    int*      tsums   = (int*)alloc((size_t)SCAN_TILES * 4);
    int*      toff    = (int*)alloc((size_t)SCAN_TILES * 4);
    float*    dinv    = (float*)alloc((size_t)N_NODES * 4);
    float*    dn      = (float*)alloc((size_t)N_NODES * DOUT * 4);
    float*    kbuf    = (float*)alloc((size_t)B_GRAPH * 128 * 4);
    float*    vbuf    = (float*)alloc((size_t)B_GRAPH * 128 * 4);
    float*    kq      = (float*)alloc((size_t)B_GRAPH * 128 * 4);
    float*    qbk     = (float*)alloc((size_t)B_GRAPH * 4);
    float*    scores  = (float*)alloc((size_t)N_NODES * 4);
    float*    enode   = (float*)alloc((size_t)N_NODES * 4);
    unsigned* mB      = (unsigned*)alloc((size_t)B_GRAPH * 4);
    float*    sB      = (float*)alloc((size_t)B_GRAPH * 4);
    unsigned* pooled  = (unsigned*)alloc((size_t)B_GRAPH * 128 * 4);
    bf16*     xcb     = (bf16*)alloc((size_t)B_GRAPH * 384 * 2);
    bf16*     h1b     = (bf16*)alloc((size_t)B_GRAPH * 1024 * 2);
    float*    h2      = (float*)alloc((size_t)B_GRAPH * 512 * 4);

    if (off > ws_size) {
        k_fail<<<(out_size + 255) / 256, 256, 0, stream>>>(out, out_size);
        return;
    }

    // ---- zero accumulators ----
    (void)hipMemsetAsync(mseg, 0, (size_t)N_NODES * H_HEADS * 4, stream);
    (void)hipMemsetAsync(sseg, 0, (size_t)N_NODES * H_HEADS * 4, stream);
    (void)hipMemsetAsync(cnt, 0, (size_t)N_NODES * 4, stream);
    (void)hipMemsetAsync(mB, 0, (size_t)B_GRAPH * 4, stream);
    (void)hipMemsetAsync(sB, 0, (size_t)B_GRAPH * 4, stream);
    (void)hipMemsetAsync(pooled, 0, (size_t)B_GRAPH * 128 * 4, stream);

    // ---- bf16 conversions / weight transposes ----
    k_f2b_pad<<<(N_NODES * XK_LD + 255) / 256, 256, 0, stream>>>(x, xb, N_NODES, FXD, XK_LD);
    k_f2bt<<<(HF * XK_LD + 255) / 256, 256, 0, stream>>>(gat_w, wt_gat, FXD, HF, XK_LD);
    k_f2bt<<<(HF * HF_LD + 255) / 256, 256, 0, stream>>>(gcn_w, wt_gcn, HF, HF, HF_LD);
    k_f2bt<<<(DOUT * HF_LD + 255) / 256, 256, 0, stream>>>(fcg1_w, wt_fcg1, HF, DOUT, HF_LD);
    k_f2bt<<<(1024 * 384 + 255) / 256, 256, 0, stream>>>(fc1_w, wt_fc1, 384, 1024, 384);
    k_f2bt<<<(512 * 1024 + 255) / 256, 256, 0, stream>>>(fc2_w, wt_fc2, 1024, 512, 1024);

    // ---- protein path ----
    k_pv<<<B_GRAPH, 256, 0, stream>>>(pvec, pfc_w, pfc_b, pv);
    k_kv<<<B_GRAPH, 256, 0, stream>>>(pv, k_w, k_b, v_w, v_b, kbuf, vbuf);
    k_kq<<<B_GRAPH, 128, 0, stream>>>(q_w, q_b, kbuf, kq, qbk);

    // ---- CSR build (hierarchical scan; R8: single-block k_scan was 100us @ 0.14% occ) ----
    k_count<<<(ETOT + 255) / 256, 256, 0, stream>>>(ei, cnt);
    k_scan_tile<<<SCAN_TILES, 256, 0, stream>>>(cnt, tsums);
    k_scan_top<<<1, 64, 0, stream>>>(tsums, toff, rowptr);
    k_scan_write<<<SCAN_TILES, 256, 0, stream>>>(cnt, toff, rowptr, cursor);
    k_scatter<<<(ETOT + 255) / 256, 256, 0, stream>>>(ei, cursor, elist);
    k_dinv<<<(N_NODES + 255) / 256, 256, 0, stream>>>(cnt, dinv);

    // ---- GAT ----
    mfma_mm<bf16, 0, 0><<<mm_grid(N_NODES, HF), 256, 0, stream>>>(
        (const ushort*)xb, XK_LD, (const ushort*)wt_gat, XK_LD, nullptr, hB, HF_LD,
        N_NODES, XK_LD, HF);
    k_att<<<(N_NODES * H_HEADS + 255) / 256, 256, 0, stream>>>(hB, gat_asrc, gat_adst,
                                                               asrc, adst);
    k_alpha_max<<<(ETOT * H_HEADS + 255) / 256, 256, 0, stream>>>(ei, asrc, adst, alpha, mseg);
    k_exp_sum<<<(ETOT * H_HEADS + 255) / 256, 256, 0, stream>>>(ei, alpha, mseg, sseg);
    k_gat_aggr_v<<<N_NODES / 4, 256, 0, stream>>>(rowptr, elist, ei, hB, alpha, sseg,
                                                  gat_b, g1);

    // ---- GCN ----
    mfma_mm<bf16, 0, 0><<<mm_grid(N_NODES, HF), 256, 0, stream>>>(
        (const ushort*)g1, HF_LD, (const ushort*)wt_gcn, HF_LD, nullptr, hB, HF_LD,
        N_NODES, HF_LD, HF);
    k_gcn_aggr_v<<<N_NODES / 4, 256, 0, stream>>>(rowptr, elist, ei, hB, dinv, gcn_b, g1);

    // ---- fc_g1 (bf16 MFMA, fp32 out, bias+relu) ----
    mfma_mm<float, 1, 1><<<mm_grid(N_NODES, DOUT), 256, 0, stream>>>(
        (const ushort*)g1, HF_LD, (const ushort*)wt_fcg1, HF_LD, fcg1_b, dn, DOUT,
        N_NODES, HF_LD, DOUT);

    // ---- cross attention + pool ----
    k_scores<<<(N_NODES * 64 + 255) / 256, 256, 0, stream>>>(dn, kq, qbk, batch, scores, mB);
    k_attn_e<<<(N_NODES + 255) / 256, 256, 0, stream>>>(scores, batch, mB, enode, sB);
    k_attend_pool<<<(N_NODES * 128 + 255) / 256, 256, 0, stream>>>(dn, vbuf, enode,
                                                                   sB, batch, pooled);
    k_xc<<<(B_GRAPH * 384 + 255) / 256, 256, 0, stream>>>(pooled, pv, xcb);

    // ---- head MLP (bf16 MFMA) ----
    mfma_mm<bf16, 1, 1><<<mm_grid(B_GRAPH, 1024), 256, 0, stream>>>(
        (const ushort*)xcb, 384, (const ushort*)wt_fc1, 384, fc1_b, h1b, 1024,
        B_GRAPH, 384, 1024);
    mfma_mm<float, 1, 1><<<mm_grid(B_GRAPH, 512), 256, 0, stream>>>(
        (const ushort*)h1b, 1024, (const ushort*)wt_fc2, 1024, fc2_b, h2, 512,
        B_GRAPH, 1024, 512);
    k_out<<<(B_GRAPH * 64 + 255) / 256, 256, 0, stream>>>(h2, out_w, out_b, out);
}